// Round 6
// baseline (421.950 us; speedup 1.0000x reference)
//
#include <hip/hip_runtime.h>
#include <math.h>

#define EPSF 1e-5f
#define GAPTH 1e-3f

// B=128, C=8, H=144, W=144, CW=1152, R=18432, TW=5, OG=2, NCLS=6, DT=256, ITC=5760
// Collapsed head: logits[row, j] = sum_k Wc[j,k] * x'[row,k] + cconst[j]
//   j 0..143 = cls, j 144..145 = ext, j 146..159 = zero pad. NP=160.

typedef __attribute__((ext_vector_type(8))) short short8v;
typedef __attribute__((ext_vector_type(4))) float f32x4;
typedef unsigned short ushort;
typedef unsigned int uint;

__device__ inline ushort f2bf(float f) {
    uint u = __float_as_uint(f);
    uint r = (u + 0x7FFFu + ((u >> 16) & 1u)) >> 16;
    return (ushort)r;
}
__device__ inline float bf2f(ushort h) { return __uint_as_float(((uint)h) << 16); }

// ---------------------------------------------------------------------------
// Build combined weights: Wc[j,k] = sum_o w2[j,o]*s[o]*w1[o,k], s = g*rsqrt(v+eps)
// cconst[j] = sum_o w2[j,o]*((b1[o]-m[o])*s[o]+bb[o]) + b2[j].  Also bf16 hi/lo.
// ---------------------------------------------------------------------------
__global__ __launch_bounds__(256) void wcomb_build(
    const float* __restrict__ w1e, const float* __restrict__ b1e, const float* __restrict__ ge,
    const float* __restrict__ bbe, const float* __restrict__ me, const float* __restrict__ ve,
    const float* __restrict__ w2e, const float* __restrict__ b2e,
    const float* __restrict__ w1c, const float* __restrict__ b1c, const float* __restrict__ gc,
    const float* __restrict__ bbc, const float* __restrict__ mc, const float* __restrict__ vc,
    const float* __restrict__ w2c, const float* __restrict__ b2c,
    float* __restrict__ Wc32, ushort* __restrict__ Wchi, ushort* __restrict__ Wclo,
    float* __restrict__ cconst)
{
    __shared__ float coef[256];
    __shared__ float csum[4];
    const int j = blockIdx.x, tid = threadIdx.x;
    const int lane = tid & 63, wid = tid >> 6;

    const float *w1 = nullptr, *w2row = nullptr, *b1 = nullptr, *g = nullptr,
                *bb = nullptr, *m = nullptr, *v = nullptr;
    float b2v = 0.f;
    int valid = 0;
    if (j < 144) {
        valid = 1; w1 = w1c; w2row = w2c + (size_t)j * 256;
        b1 = b1c; g = gc; bb = bbc; m = mc; v = vc; b2v = b2c[j];
    } else if (j < 146) {
        valid = 1; w1 = w1e; w2row = w2e + (size_t)(j - 144) * 256;
        b1 = b1e; g = ge; bb = bbe; m = me; v = ve; b2v = b2e[j - 144];
    }

    float cf = 0.f, cc = 0.f;
    if (valid) {
        float s = g[tid] * rsqrtf(v[tid] + EPSF);
        float w2v = w2row[tid];
        cf = w2v * s;
        cc = w2v * ((b1[tid] - m[tid]) * s + bb[tid]);
    }
    coef[tid] = cf;
    float t = cc;
#pragma unroll
    for (int off = 32; off; off >>= 1) t += __shfl_xor(t, off);
    if (lane == 0) csum[wid] = t;
    __syncthreads();
    if (tid == 0) cconst[j] = valid ? ((csum[0] + csum[1]) + (csum[2] + csum[3]) + b2v) : 0.f;

    for (int k = tid; k < 1152; k += 256) {
        float acc = 0.f;
        if (valid) {
            for (int o = 0; o < 256; o++) acc += coef[o] * w1[(size_t)o * 1152 + k];
        }
        Wc32[(size_t)j * 1152 + k] = acc;
        ushort hi = f2bf(acc);
        Wchi[(size_t)j * 1152 + k] = hi;
        Wclo[(size_t)j * 1152 + k] = f2bf(acc - bf2f(hi));
    }
}

__global__ void zero_counters(int* __restrict__ cand_count)
{
    *cand_count = 0;
}

// ---------------------------------------------------------------------------
// logits GEMM: M=18432, N=160(146 used), K=1152, split-bf16 MFMA (hi/lo, 3 products)
// BM=64, BN=160, BK=32; 4 waves as 2m x 2n; wave tile 32x80 (2x5 16x16 frags)
// PATCH=1: x columns in argmax window replaced by refined5 (predicated on *flag)
// ---------------------------------------------------------------------------
template<int PATCH>
__global__ __launch_bounds__(256) void logits_gemm(
    const float* __restrict__ x, const ushort* __restrict__ Wchi, const ushort* __restrict__ Wclo,
    const float* __restrict__ cconst, const int* __restrict__ amax,
    const float* __restrict__ refined5, const int* __restrict__ flag,
    float* __restrict__ logits)
{
    __shared__ ushort Ahi[64][40], Alo[64][40], Bhi[160][40], Blo[160][40];
    const int tid = threadIdx.x;
    const int lane = tid & 63, wid = tid >> 6;
    const int wm = wid & 1, wn = wid >> 1;
    const int rb = blockIdx.x * 64;

    // A staging coords (fixed per thread): 8 contiguous k per thread
    const int rl = tid >> 2, kk = (tid & 3) << 3;
    const int arow = rb + rl;
    const int ab = arow / 144, ahh = arow - ab * 144;
    int fl = 0, pa = 0;
    if (PATCH) { fl = *flag; if (fl) pa = amax[arow]; }

    // B staging coords
    const int br0 = tid >> 2, bk0 = (tid & 3) << 3;          // rows 0..63
    const int br2 = 128 + (tid >> 3), bk2 = (tid & 7) << 2;  // rows 128..159

    float av[8];
    short8v vbh0, vbl0, vbh1, vbl1;
    ushort vbh2[4], vbl2[4];

    auto LOAD = [&](int kb) {
        int k1 = kb + kk, c1 = k1 / 144, w1 = k1 - c1 * 144;
        const float4 t0 = *reinterpret_cast<const float4*>(
            x + (((size_t)(ab * 8 + c1) * 144 + ahh) * 144 + w1));
        int k2 = k1 + 4, c2 = k2 / 144, w2 = k2 - c2 * 144;
        const float4 t1 = *reinterpret_cast<const float4*>(
            x + (((size_t)(ab * 8 + c2) * 144 + ahh) * 144 + w2));
        av[0] = t0.x; av[1] = t0.y; av[2] = t0.z; av[3] = t0.w;
        av[4] = t1.x; av[5] = t1.y; av[6] = t1.z; av[7] = t1.w;
        if (PATCH && fl) {
            int d0 = w1 - pa + 2;
#pragma unroll
            for (int q = 0; q < 4; q++) {
                int dw = d0 + q;
                if (dw >= 0 && dw < 5)
                    av[q] = refined5[(size_t)ab * 5760 + (c1 * 144 + ahh) * 5 + dw];
            }
            int d1 = w2 - pa + 2;
#pragma unroll
            for (int q = 0; q < 4; q++) {
                int dw = d1 + q;
                if (dw >= 0 && dw < 5)
                    av[4 + q] = refined5[(size_t)ab * 5760 + (c2 * 144 + ahh) * 5 + dw];
            }
        }
        size_t o0 = (size_t)br0 * 1152 + kb + bk0;
        vbh0 = *reinterpret_cast<const short8v*>(Wchi + o0);
        vbl0 = *reinterpret_cast<const short8v*>(Wclo + o0);
        size_t o1 = (size_t)(br0 + 64) * 1152 + kb + bk0;
        vbh1 = *reinterpret_cast<const short8v*>(Wchi + o1);
        vbl1 = *reinterpret_cast<const short8v*>(Wclo + o1);
        size_t o2 = (size_t)br2 * 1152 + kb + bk2;
#pragma unroll
        for (int q = 0; q < 4; q++) { vbh2[q] = Wchi[o2 + q]; vbl2[q] = Wclo[o2 + q]; }
    };

    auto STORE = [&]() {
        ushort h[8], l[8];
#pragma unroll
        for (int q = 0; q < 8; q++) {
            h[q] = f2bf(av[q]);
            l[q] = f2bf(av[q] - bf2f(h[q]));
        }
#pragma unroll
        for (int q = 0; q < 8; q++) { Ahi[rl][kk + q] = h[q]; Alo[rl][kk + q] = l[q]; }
        *reinterpret_cast<short8v*>(&Bhi[br0][bk0]) = vbh0;
        *reinterpret_cast<short8v*>(&Blo[br0][bk0]) = vbl0;
        *reinterpret_cast<short8v*>(&Bhi[br0 + 64][bk0]) = vbh1;
        *reinterpret_cast<short8v*>(&Blo[br0 + 64][bk0]) = vbl1;
#pragma unroll
        for (int q = 0; q < 4; q++) { Bhi[br2][bk2 + q] = vbh2[q]; Blo[br2][bk2 + q] = vbl2[q]; }
    };

    f32x4 acc[2][5];
#pragma unroll
    for (int mt = 0; mt < 2; mt++)
#pragma unroll
        for (int nt = 0; nt < 5; nt++) acc[mt][nt] = (f32x4){0.f, 0.f, 0.f, 0.f};

    const int fr = lane & 15, fg = (lane >> 4) << 3;

    LOAD(0);
    for (int t = 0; t < 36; t++) {
        STORE();
        if (t < 35) LOAD((t + 1) * 32);
        __syncthreads();
        short8v ah0 = *reinterpret_cast<const short8v*>(&Ahi[wm * 32 + fr][fg]);
        short8v al0 = *reinterpret_cast<const short8v*>(&Alo[wm * 32 + fr][fg]);
        short8v ah1 = *reinterpret_cast<const short8v*>(&Ahi[wm * 32 + 16 + fr][fg]);
        short8v al1 = *reinterpret_cast<const short8v*>(&Alo[wm * 32 + 16 + fr][fg]);
#pragma unroll
        for (int nt = 0; nt < 5; nt++) {
            short8v bh = *reinterpret_cast<const short8v*>(&Bhi[wn * 80 + nt * 16 + fr][fg]);
            short8v bl = *reinterpret_cast<const short8v*>(&Blo[wn * 80 + nt * 16 + fr][fg]);
            acc[0][nt] = __builtin_amdgcn_mfma_f32_16x16x32_bf16(ah0, bh, acc[0][nt], 0, 0, 0);
            acc[0][nt] = __builtin_amdgcn_mfma_f32_16x16x32_bf16(ah0, bl, acc[0][nt], 0, 0, 0);
            acc[0][nt] = __builtin_amdgcn_mfma_f32_16x16x32_bf16(al0, bh, acc[0][nt], 0, 0, 0);
            acc[1][nt] = __builtin_amdgcn_mfma_f32_16x16x32_bf16(ah1, bh, acc[1][nt], 0, 0, 0);
            acc[1][nt] = __builtin_amdgcn_mfma_f32_16x16x32_bf16(ah1, bl, acc[1][nt], 0, 0, 0);
            acc[1][nt] = __builtin_amdgcn_mfma_f32_16x16x32_bf16(al1, bh, acc[1][nt], 0, 0, 0);
        }
        __syncthreads();
    }

    // epilogue: C/D layout col=lane&15, row=(lane>>4)*4+i  [m89-verified]
#pragma unroll
    for (int mt = 0; mt < 2; mt++) {
#pragma unroll
        for (int nt = 0; nt < 5; nt++) {
            int gcol = wn * 80 + nt * 16 + fr;
            if (gcol < 146) {
                float cc = cconst[gcol];
                float* dst = logits + (size_t)(rb + wm * 32 + mt * 16 + ((lane >> 4) << 2)) * 160 + gcol;
#pragma unroll
                for (int i = 0; i < 4; i++)
                    dst[(size_t)i * 160] = acc[mt][nt][i] + cc;
            }
        }
    }
}

// ---------------------------------------------------------------------------
// merged softmax: cls over cols 0..143 (+argmax & top-2 gap -> candidate list),
// ext over cols 144..145.  One wave per row, 4 rows per block.
// ---------------------------------------------------------------------------
__global__ __launch_bounds__(256) void softmax_heads(
    const float* __restrict__ logits, float* __restrict__ out_cls, float* __restrict__ out_ext,
    int* __restrict__ amax, float* __restrict__ partials,
    int* __restrict__ cand_count, int* __restrict__ cand_list)
{
    __shared__ float ps[4];
    int row = blockIdx.x * 4 + (threadIdx.x >> 6);
    int lane = threadIdx.x & 63;
    const float* L = logits + (size_t)row * 160;
    float v0 = L[lane];
    float v1 = L[lane + 64];
    float v2 = (lane < 16) ? L[lane + 128] : -3.0e38f;
    // argmax (first-max tie rule) + top-2 values
    float m = v0; int mi = lane;
    if (v1 > m) { m = v1; mi = lane + 64; }
    if (v2 > m) { m = v2; mi = lane + 128; }
    float m1 = v0, m2 = -3.0e38f;
    if (v1 > m1) { m2 = m1; m1 = v1; } else m2 = v1;
    if (v2 > m1) { m2 = m1; m1 = v2; } else m2 = fmaxf(m2, v2);
#pragma unroll
    for (int off = 32; off; off >>= 1) {
        float om = __shfl_xor(m, off);
        int   oi = __shfl_xor(mi, off);
        if (om > m || (om == m && oi < mi)) { m = om; mi = oi; }
        float om1 = __shfl_xor(m1, off);
        float om2 = __shfl_xor(m2, off);
        float nm1 = fmaxf(m1, om1);
        m2 = fmaxf(fminf(m1, om1), fmaxf(m2, om2));
        m1 = nm1;
    }
    float e0 = expf(v0 - m), e1 = expf(v1 - m);
    float e2 = (lane < 16) ? expf(v2 - m) : 0.f;
    float s = e0 + e1 + e2;
#pragma unroll
    for (int off = 32; off; off >>= 1) s += __shfl_xor(s, off);
    float inv = 1.f / s;
    float* O = out_cls + (size_t)row * 144;
    O[lane] = e0 * inv;
    O[lane + 64] = e1 * inv;
    if (lane < 16) O[lane + 128] = e2 * inv;

    // ext head (2 logits)
    float l0 = L[144], l1 = L[145];
    float mx = fmaxf(l0, l1);
    float ee0 = expf(l0 - mx), ee1 = expf(l1 - mx);
    float einv = 1.f / (ee0 + ee1);
    float p0 = ee0 * einv;
    if (lane == 0) {
        out_ext[(size_t)row * 2] = p0;
        out_ext[(size_t)row * 2 + 1] = ee1 * einv;
        if (amax != nullptr) {
            amax[row] = mi;
            if (m1 - m2 < GAPTH) {
                int slot = atomicAdd(cand_count, 1);
                cand_list[slot] = row;
            }
        }
    }
    if (partials != nullptr) {
        if (lane == 0) ps[threadIdx.x >> 6] = p0;
        __syncthreads();
        if (threadIdx.x == 0) partials[blockIdx.x] = (ps[0] + ps[1]) + (ps[2] + ps[3]);
    }
}

__global__ __launch_bounds__(256) void reduce_flag(const float* __restrict__ partials, int n,
                                                   int* __restrict__ flag)
{
    __shared__ float sm[256];
    int tid = threadIdx.x;
    float s = 0.f;
    for (int i = tid; i < n; i += 256) s += partials[i];
    sm[tid] = s; __syncthreads();
    for (int off = 128; off; off >>= 1) {
        if (tid < off) sm[tid] += sm[tid + off];
        __syncthreads();
    }
    if (tid == 0) *flag = (sm[0] * (1.f / 18432.f) > 0.3f) ? 1 : 0;
}

// ---------------------------------------------------------------------------
// fixup over compacted candidate list: exact f32 two-stage recompute of argmax
// ---------------------------------------------------------------------------
__global__ __launch_bounds__(256) void fixup_list(
    const int* __restrict__ cand_count, const int* __restrict__ cand_list,
    const float* __restrict__ x,
    const float* __restrict__ w1c, const float* __restrict__ b1c,
    const float* __restrict__ gc, const float* __restrict__ bbc,
    const float* __restrict__ mc, const float* __restrict__ vc,
    const float* __restrict__ w2c, const float* __restrict__ b2c,
    int* __restrict__ amax)
{
    __shared__ float xrow[1152];
    __shared__ float hsh[256];
    __shared__ float Lsh[144];
    const int tid = threadIdx.x;
    const int lane = tid & 63, wid = tid >> 6;
    const int n = *cand_count;

    for (int ci = blockIdx.x; ci < n; ci += gridDim.x) {
        const int row = cand_list[ci];
        const int b = row / 144, hh = row - b * 144;
        for (int e = tid; e < 1152; e += 256) {
            int c = e / 144, w = e - c * 144;
            xrow[e] = x[(((size_t)(b * 8 + c) * 144 + hh) * 144) + w];
        }
        __syncthreads();
        for (int oo = 0; oo < 64; oo++) {
            int o = wid * 64 + oo;
            const float* wr = w1c + (size_t)o * 1152;
            float a = 0.f;
#pragma unroll
            for (int j = 0; j < 18; j++) a += wr[lane + 64 * j] * xrow[lane + 64 * j];
#pragma unroll
            for (int off = 32; off; off >>= 1) a += __shfl_xor(a, off);
            if (lane == 0) {
                float sc = gc[o] * rsqrtf(vc[o] + EPSF);
                hsh[o] = (a + b1c[o] - mc[o]) * sc + bbc[o];
            }
        }
        __syncthreads();
        for (int jj = 0; jj < 36; jj++) {
            int j = wid * 36 + jj;
            const float* wr = w2c + (size_t)j * 256;
            float a = wr[lane] * hsh[lane] + wr[lane + 64] * hsh[lane + 64]
                    + wr[lane + 128] * hsh[lane + 128] + wr[lane + 192] * hsh[lane + 192];
#pragma unroll
            for (int off = 32; off; off >>= 1) a += __shfl_xor(a, off);
            if (lane == 0) Lsh[j] = a + b2c[j];
        }
        __syncthreads();
        if (tid == 0) {
            int bi = 0; float bv = Lsh[0];
            for (int j = 1; j < 144; j++) if (Lsh[j] > bv) { bv = Lsh[j]; bi = j; }
            amax[row] = bi;
        }
        __syncthreads();
    }
}

// ---------------------------------------------------------------------------
// gather patches from zero-padded x at argmax windows
// ---------------------------------------------------------------------------
__global__ __launch_bounds__(256) void gather_patches(const float* __restrict__ x,
    const int* __restrict__ amax, float* __restrict__ patches)
{
    int idx = blockIdx.x * 256 + threadIdx.x;
    int b = idx / 5760, j = idx - b * 5760;
    int c = j / 720, r2 = j - c * 720;
    int hh = r2 / 5, tw = r2 - hh * 5;
    int a = amax[b * 144 + hh];
    int w = a + tw - 2;
    patches[idx] = (w >= 0 && w < 144) ? x[(((size_t)(b * 8 + c) * 144 + hh) * 144) + w] : 0.f;
}

// ---------------------------------------------------------------------------
// tok GEMM, K-split into 8 chunks of 720 (deterministic 2-stage)
// ---------------------------------------------------------------------------
__global__ __launch_bounds__(256) void tok_partial(const float* __restrict__ patches,
    const float* __restrict__ tok_w, float* __restrict__ tpart)
{
    __shared__ float P[720];
    int b = blockIdx.x, ks = blockIdx.y, tid = threadIdx.x;
    for (int e = tid; e < 720; e += 256) P[e] = patches[(size_t)b * 5760 + ks * 720 + e];
    __syncthreads();
    float acc = 0.f;
    const float* wbase = tok_w + (size_t)ks * 720 * 256;
    for (int k = 0; k < 720; k++) acc += P[k] * wbase[(size_t)k * 256 + tid];
    tpart[((size_t)b * 8 + ks) * 256 + tid] = acc;
}

// ---------------------------------------------------------------------------
// attn_front: tok_finish + LN1(x6) + qkv (q only for token 5) + attention row 5
// + out-proj token 5 + residual + LN2.  One block per batch elem, 512 threads.
// Only token 5 survives the reference scatter, and only attention mixes tokens.
// ---------------------------------------------------------------------------
__global__ __launch_bounds__(512) void attn_front(
    const float* __restrict__ tpart, const float* __restrict__ tok_b,
    const float* __restrict__ emb,
    const float* __restrict__ ln1_g, const float* __restrict__ ln1_b,
    const float* __restrict__ qkv_w,
    const float* __restrict__ out_w, const float* __restrict__ out_b,
    const float* __restrict__ ln2_g, const float* __restrict__ ln2_b,
    float* __restrict__ z2_5, float* __restrict__ t5out)
{
    __shared__ float s[256];
    __shared__ float z[6][256];
    __shared__ float qk[6][192];   // cols: 0-63 q (row5 only), 64-127 k, 128-191 v
    __shared__ float att[2][6];
    __shared__ float o5[64];
    __shared__ float t5[256];
    __shared__ float stat[2];
    const int b = blockIdx.x, tid = threadIdx.x;
    const int lane = tid & 63, wv = tid >> 6;

    if (tid < 256) {
        float a = tok_b[tid];
        for (int ks = 0; ks < 8; ks++) a += tpart[((size_t)b * 8 + ks) * 256 + tid];
        s[tid] = a;
    }
    __syncthreads();

    // LN1: wave wv handles token wv (wv<6)
    if (wv < 6) {
        float y[4], s1 = 0.f, s2 = 0.f;
#pragma unroll
        for (int q = 0; q < 4; q++) {
            int k = lane + 64 * q;
            y[q] = s[k] + emb[wv * 256 + k];
            s1 += y[q]; s2 += y[q] * y[q];
        }
#pragma unroll
        for (int off = 32; off; off >>= 1) { s1 += __shfl_xor(s1, off); s2 += __shfl_xor(s2, off); }
        float mu = s1 * (1.f / 256.f);
        float var = s2 * (1.f / 256.f) - mu * mu;
        float rs = rsqrtf(var + EPSF);
#pragma unroll
        for (int q = 0; q < 4; q++) {
            int k = lane + 64 * q;
            z[wv][k] = (y[q] - mu) * rs * ln1_g[k] + ln1_b[k];
        }
    }
    __syncthreads();

    // qkv dots: d<768 -> k/v for token i=d>>7, col c=64+(d&127); d>=768 -> q5, c=d-768
    for (int d = tid; d < 832; d += 512) {
        int i, c;
        if (d < 768) { i = d >> 7; c = 64 + (d & 127); }
        else         { i = 5;      c = d - 768; }
        float a = 0.f;
#pragma unroll 4
        for (int k = 0; k < 256; k++) a += z[i][k] * qkv_w[(size_t)k * 192 + c];
        qk[i][c] = a;
    }
    __syncthreads();

    // attention row 5 only
    if (tid < 12) {
        int h = tid / 6, j = tid - h * 6;
        float a = 0.f;
#pragma unroll
        for (int d = 0; d < 32; d++) a += qk[5][h * 32 + d] * qk[j][64 + h * 32 + d];
        att[h][j] = a * 0.17677669529663687f;
    }
    __syncthreads();
    if (tid < 2) {
        float m = -3.0e38f;
        for (int j = 0; j < 6; j++) m = fmaxf(m, att[tid][j]);
        float ssum = 0.f;
        for (int j = 0; j < 6; j++) { float e = expf(att[tid][j] - m); att[tid][j] = e; ssum += e; }
        float inv = 1.f / ssum;
        for (int j = 0; j < 6; j++) att[tid][j] *= inv;
    }
    __syncthreads();
    if (tid < 64) {
        int h = tid >> 5;
        float a = 0.f;
#pragma unroll
        for (int j = 0; j < 6; j++) a += att[h][j] * qk[j][128 + tid];
        o5[tid] = a;
    }
    __syncthreads();

    // out-proj token 5 + residual
    if (tid < 256) {
        float a = out_b[tid] + s[tid] + emb[5 * 256 + tid];
#pragma unroll 4
        for (int d = 0; d < 64; d++) a += o5[d] * out_w[(size_t)d * 256 + tid];
        t5[tid] = a;
    }
    __syncthreads();

    // LN2 stats (wave 0)
    if (wv == 0) {
        float s1 = 0.f, s2 = 0.f;
#pragma unroll
        for (int q = 0; q < 4; q++) { float vv = t5[lane + 64 * q]; s1 += vv; s2 += vv * vv; }
#pragma unroll
        for (int off = 32; off; off >>= 1) { s1 += __shfl_xor(s1, off); s2 += __shfl_xor(s2, off); }
        if (lane == 0) {
            float mu = s1 * (1.f / 256.f);
            float var = s2 * (1.f / 256.f) - mu * mu;
            stat[0] = mu; stat[1] = rsqrtf(var + EPSF);
        }
    }
    __syncthreads();
    if (tid < 256) {
        t5out[(size_t)b * 256 + tid] = t5[tid];
        z2_5[(size_t)b * 256 + tid] = (t5[tid] - stat[0]) * stat[1] * ln2_g[tid] + ln2_b[tid];
    }
}

// ---------------------------------------------------------------------------
// ff1 + exact gelu for token 5: f5[b, jj] over N=512 split in 2 blocks
// ---------------------------------------------------------------------------
__global__ __launch_bounds__(256) void ff1_gelu(
    const float* __restrict__ z2_5, const float* __restrict__ ff_w1,
    const float* __restrict__ ff_b1, float* __restrict__ f5)
{
    __shared__ float zsh[256];
    const int b = blockIdx.x, half = blockIdx.y, tid = threadIdx.x;
    zsh[tid] = z2_5[(size_t)b * 256 + tid];
    __syncthreads();
    const int jj = half * 256 + tid;
    float a = ff_b1[jj];
#pragma unroll 4
    for (int k = 0; k < 256; k++) a += zsh[k] * ff_w1[(size_t)k * 512 + jj];
    f5[(size_t)b * 512 + jj] = 0.5f * a * (1.f + erff(a * 0.70710678118654752f));
}

// ---------------------------------------------------------------------------
// ff2 + residual + LNF for token 5 -> tfin
// ---------------------------------------------------------------------------
__global__ __launch_bounds__(256) void ff2_lnf(
    const float* __restrict__ f5, const float* __restrict__ ff_w2,
    const float* __restrict__ ff_b2, const float* __restrict__ t5in,
    const float* __restrict__ lnf_g, const float* __restrict__ lnf_b,
    float* __restrict__ tfin)
{
    __shared__ float fsh[512];
    __shared__ float tsh[256];
    __shared__ float stat[2];
    const int b = blockIdx.x, tid = threadIdx.x;
    const int lane = tid & 63;
    fsh[tid] = f5[(size_t)b * 512 + tid];
    fsh[tid + 256] = f5[(size_t)b * 512 + tid + 256];
    __syncthreads();
    float a = ff_b2[tid] + t5in[(size_t)b * 256 + tid];
#pragma unroll 4
    for (int k = 0; k < 512; k++) a += fsh[k] * ff_w2[(size_t)k * 256 + tid];
    tsh[tid] = a;
    __syncthreads();
    if (tid < 64) {
        float s1 = 0.f, s2 = 0.f;
#pragma unroll
        for (int q = 0; q < 4; q++) { float vv = tsh[lane + 64 * q]; s1 += vv; s2 += vv * vv; }
#pragma unroll
        for (int off = 32; off; off >>= 1) { s1 += __shfl_xor(s1, off); s2 += __shfl_xor(s2, off); }
        if (lane == 0) {
            float mu = s1 * (1.f / 256.f);
            float var = s2 * (1.f / 256.f) - mu * mu;
            stat[0] = mu; stat[1] = rsqrtf(var + EPSF);
        }
    }
    __syncthreads();
    tfin[(size_t)b * 256 + tid] = (tsh[tid] - stat[0]) * stat[1] * lnf_g[tid] + lnf_b[tid];
}

// ---------------------------------------------------------------------------
// fin GEMM for token 5: refined5[b,n] = tfin[b,:] @ fin_w[:,n] + fin_b[n]
// ---------------------------------------------------------------------------
__global__ __launch_bounds__(256) void fin_gemm(const float* __restrict__ tfin,
    const float* __restrict__ fin_w, const float* __restrict__ fin_b, float* __restrict__ refined5)
{
    __shared__ float tf[16][256];
    int tid = threadIdx.x;
    int nb = blockIdx.x * 256 + tid;
    int bg = blockIdx.y * 16;
    for (int e = tid; e < 4096; e += 256) tf[e >> 8][e & 255] = tfin[(size_t)(bg + (e >> 8)) * 256 + (e & 255)];
    __syncthreads();
    if (nb < 5760) {
        float acc[16];
#pragma unroll
        for (int bb = 0; bb < 16; bb++) acc[bb] = 0.f;
        for (int k = 0; k < 256; k++) {
            float wv = fin_w[(size_t)k * 5760 + nb];
#pragma unroll
            for (int bb = 0; bb < 16; bb++) acc[bb] += tf[bb][k] * wv;
        }
        float fb = fin_b[nb];
#pragma unroll
        for (int bb = 0; bb < 16; bb++)
            refined5[(size_t)(bg + bb) * 5760 + nb] = acc[bb] + fb;
    }
}

// ---------------------------------------------------------------------------
extern "C" void kernel_launch(void* const* d_in, const int* in_sizes, int n_in,
                              void* d_out, int out_size, void* d_ws, size_t ws_size,
                              hipStream_t stream)
{
    const float* x      = (const float*)d_in[0];
    const float* ext_w1 = (const float*)d_in[1];
    const float* ext_b1 = (const float*)d_in[2];
    const float* ext_g  = (const float*)d_in[3];
    const float* ext_bb = (const float*)d_in[4];
    const float* ext_m  = (const float*)d_in[5];
    const float* ext_v  = (const float*)d_in[6];
    const float* ext_w2 = (const float*)d_in[7];
    const float* ext_b2 = (const float*)d_in[8];
    const float* cls_w1 = (const float*)d_in[9];
    const float* cls_b1 = (const float*)d_in[10];
    const float* cls_g  = (const float*)d_in[11];
    const float* cls_bb = (const float*)d_in[12];
    const float* cls_m  = (const float*)d_in[13];
    const float* cls_v  = (const float*)d_in[14];
    const float* cls_w2 = (const float*)d_in[15];
    const float* cls_b2 = (const float*)d_in[16];
    const float* tok_w  = (const float*)d_in[17];
    const float* tok_b  = (const float*)d_in[18];
    const float* emb    = (const float*)d_in[19];
    const float* ln1_g  = (const float*)d_in[20];
    const float* ln1_b  = (const float*)d_in[21];
    const float* qkv_w  = (const float*)d_in[22];
    const float* out_w  = (const float*)d_in[23];
    const float* out_b  = (const float*)d_in[24];
    const float* ln2_g  = (const float*)d_in[25];
    const float* ln2_b  = (const float*)d_in[26];
    const float* ff_w1  = (const float*)d_in[27];
    const float* ff_b1  = (const float*)d_in[28];
    const float* ff_w2  = (const float*)d_in[29];
    const float* ff_b2  = (const float*)d_in[30];
    const float* lnf_g  = (const float*)d_in[31];
    const float* lnf_b  = (const float*)d_in[32];
    const float* fin_w  = (const float*)d_in[33];
    const float* fin_b  = (const float*)d_in[34];

    float* out = (float*)d_out;
    float* ws  = (float*)d_ws;

    // workspace layout (float offsets)
    float*  Wc32     = ws;                       // 160*1152 = 184320
    float*  cconst   = ws + 184320;              // 160
    ushort* Wchi     = (ushort*)(ws + 184480);   // 184320 ushorts
    ushort* Wclo     = (ushort*)(ws + 276640);   // 184320 ushorts
    float*  logits   = ws + 368800;              // 18432*160 = 2949120
    float*  partials = ws + 3317920;             // 4608
    float*  patches  = ws + 3322528;             // 737280
    float*  z2_5     = ws + 4059808;             // 32768
    float*  t5buf    = ws + 4092576;             // 32768
    float*  f5buf    = ws + 4125344;             // 65536
    float*  tfin     = ws + 4256416;             // 32768
    float*  refined5 = ws + 4289184;             // 737280
    float*  tpart    = ws + 5026464;             // 262144
    int*    amax     = (int*)(ws + 5288608);     // 18432
    int*    flag     = (int*)(ws + 5307040);     // 1
    int*    cand_cnt = (int*)(ws + 5307041);     // 1
    int*    cand_lst = (int*)(ws + 5307042);     // 18432

    // output offsets: ext | cls | ext2 | cls2
    float* out_ext  = out;
    float* out_cls  = out + 36864;
    float* out_ext2 = out + 2691072;
    float* out_cls2 = out + 2727936;

    dim3 blk(256);

    // combined weights (independent of x)
    wcomb_build<<<160, blk, 0, stream>>>(
        ext_w1, ext_b1, ext_g, ext_bb, ext_m, ext_v, ext_w2, ext_b2,
        cls_w1, cls_b1, cls_g, cls_bb, cls_m, cls_v, cls_w2, cls_b2,
        Wc32, Wchi, Wclo, cconst);
    zero_counters<<<1, 1, 0, stream>>>(cand_cnt);

    // pass 1
    logits_gemm<0><<<288, blk, 0, stream>>>(x, Wchi, Wclo, cconst,
        nullptr, nullptr, nullptr, logits);
    softmax_heads<<<4608, blk, 0, stream>>>(logits, out_cls, out_ext, amax, partials,
        cand_cnt, cand_lst);
    reduce_flag<<<1, blk, 0, stream>>>(partials, 4608, flag);
    fixup_list<<<256, blk, 0, stream>>>(cand_cnt, cand_lst, x,
        cls_w1, cls_b1, cls_g, cls_bb, cls_m, cls_v, cls_w2, cls_b2, amax);

    // refine chain (always computed; application predicated on flag)
    gather_patches<<<2880, blk, 0, stream>>>(x, amax, patches);
    tok_partial<<<dim3(128, 8), blk, 0, stream>>>(patches, tok_w, tpart);
    attn_front<<<128, dim3(512), 0, stream>>>(tpart, tok_b, emb, ln1_g, ln1_b, qkv_w,
        out_w, out_b, ln2_g, ln2_b, z2_5, t5buf);
    ff1_gelu<<<dim3(128, 2), blk, 0, stream>>>(z2_5, ff_w1, ff_b1, f5buf);
    ff2_lnf<<<128, blk, 0, stream>>>(f5buf, ff_w2, ff_b2, t5buf, lnf_g, lnf_b, tfin);
    fin_gemm<<<dim3(23, 8), blk, 0, stream>>>(tfin, fin_w, fin_b, refined5);

    // pass 2 (x2 patched on the fly)
    logits_gemm<1><<<288, blk, 0, stream>>>(x, Wchi, Wclo, cconst,
        amax, refined5, flag, logits);
    softmax_heads<<<4608, blk, 0, stream>>>(logits, out_cls2, out_ext2, nullptr, nullptr,
        nullptr, nullptr);
}

// Round 7
// 410.399 us; speedup vs baseline: 1.0281x; 1.0281x over previous
//
#include <hip/hip_runtime.h>
#include <math.h>

#define EPSF 1e-5f
#define GAPTH 1e-3f

// B=128, C=8, H=144, W=144, CW=1152, R=18432, TW=5, OG=2, NCLS=6, DT=256, ITC=5760
// Collapsed head: logits[row, j] = sum_k Wc[j,k] * x'[row,k] + cconst[j]
//   j 0..143 = cls, j 144..145 = ext, j 146..159 = zero pad. NP=160.

typedef __attribute__((ext_vector_type(8))) short short8v;
typedef __attribute__((ext_vector_type(4))) float f32x4;
typedef unsigned short ushort;
typedef unsigned int uint;

__device__ inline ushort f2bf(float f) {
    uint u = __float_as_uint(f);
    uint r = (u + 0x7FFFu + ((u >> 16) & 1u)) >> 16;
    return (ushort)r;
}
__device__ inline float bf2f(ushort h) { return __uint_as_float(((uint)h) << 16); }

// ---------------------------------------------------------------------------
// Build combined weights: Wc[j,k] = sum_o w2[j,o]*s[o]*w1[o,k], s = g*rsqrt(v+eps)
// cconst[j] = sum_o w2[j,o]*((b1[o]-m[o])*s[o]+bb[o]) + b2[j].  Also bf16 hi/lo.
// ---------------------------------------------------------------------------
__global__ __launch_bounds__(256) void wcomb_build(
    const float* __restrict__ w1e, const float* __restrict__ b1e, const float* __restrict__ ge,
    const float* __restrict__ bbe, const float* __restrict__ me, const float* __restrict__ ve,
    const float* __restrict__ w2e, const float* __restrict__ b2e,
    const float* __restrict__ w1c, const float* __restrict__ b1c, const float* __restrict__ gc,
    const float* __restrict__ bbc, const float* __restrict__ mc, const float* __restrict__ vc,
    const float* __restrict__ w2c, const float* __restrict__ b2c,
    float* __restrict__ Wc32, ushort* __restrict__ Wchi, ushort* __restrict__ Wclo,
    float* __restrict__ cconst)
{
    __shared__ float coef[256];
    __shared__ float csum[4];
    const int j = blockIdx.x, tid = threadIdx.x;
    const int lane = tid & 63, wid = tid >> 6;

    const float *w1 = nullptr, *w2row = nullptr, *b1 = nullptr, *g = nullptr,
                *bb = nullptr, *m = nullptr, *v = nullptr;
    float b2v = 0.f;
    int valid = 0;
    if (j < 144) {
        valid = 1; w1 = w1c; w2row = w2c + (size_t)j * 256;
        b1 = b1c; g = gc; bb = bbc; m = mc; v = vc; b2v = b2c[j];
    } else if (j < 146) {
        valid = 1; w1 = w1e; w2row = w2e + (size_t)(j - 144) * 256;
        b1 = b1e; g = ge; bb = bbe; m = me; v = ve; b2v = b2e[j - 144];
    }

    float cf = 0.f, cc = 0.f;
    if (valid) {
        float s = g[tid] * rsqrtf(v[tid] + EPSF);
        float w2v = w2row[tid];
        cf = w2v * s;
        cc = w2v * ((b1[tid] - m[tid]) * s + bb[tid]);
    }
    coef[tid] = cf;
    float t = cc;
#pragma unroll
    for (int off = 32; off; off >>= 1) t += __shfl_xor(t, off);
    if (lane == 0) csum[wid] = t;
    __syncthreads();
    if (tid == 0) cconst[j] = valid ? ((csum[0] + csum[1]) + (csum[2] + csum[3]) + b2v) : 0.f;

    for (int k = tid; k < 1152; k += 256) {
        float acc = 0.f;
        if (valid) {
            for (int o = 0; o < 256; o++) acc += coef[o] * w1[(size_t)o * 1152 + k];
        }
        Wc32[(size_t)j * 1152 + k] = acc;
        ushort hi = f2bf(acc);
        Wchi[(size_t)j * 1152 + k] = hi;
        Wclo[(size_t)j * 1152 + k] = f2bf(acc - bf2f(hi));
    }
}

__global__ void zero_counters(int* __restrict__ cand_count)
{
    *cand_count = 0;
}

// ---------------------------------------------------------------------------
// tiled transpose: src[R][Cc] -> dst[Cc][R]
// ---------------------------------------------------------------------------
__global__ __launch_bounds__(256) void transpose_w(
    const float* __restrict__ src, float* __restrict__ dst, int R, int Cc)
{
    __shared__ float tile[32][33];
    const int rb = blockIdx.y * 32, cb = blockIdx.x * 32;
    const int tx = threadIdx.x & 31, ty = threadIdx.x >> 5;   // ty 0..7
#pragma unroll
    for (int i = ty; i < 32; i += 8) {
        int r = rb + i, c = cb + tx;
        tile[i][tx] = (r < R && c < Cc) ? src[(size_t)r * Cc + c] : 0.f;
    }
    __syncthreads();
#pragma unroll
    for (int i = ty; i < 32; i += 8) {
        int c = cb + i, r = rb + tx;
        if (c < Cc && r < R) dst[(size_t)c * R + r] = tile[tx][i];
    }
}

// ---------------------------------------------------------------------------
// logits GEMM: M=18432, N=160(146 used), K=1152, split-bf16 MFMA (hi/lo, 3 products)
// BM=64, BN=160, BK=32; 4 waves as 2m x 2n; wave tile 32x80 (2x5 16x16 frags)
// PATCH=1: x columns in argmax window replaced by refined5 (predicated on *flag)
// ---------------------------------------------------------------------------
template<int PATCH>
__global__ __launch_bounds__(256) void logits_gemm(
    const float* __restrict__ x, const ushort* __restrict__ Wchi, const ushort* __restrict__ Wclo,
    const float* __restrict__ cconst, const int* __restrict__ amax,
    const float* __restrict__ refined5, const int* __restrict__ flag,
    float* __restrict__ logits)
{
    __shared__ ushort Ahi[64][40], Alo[64][40], Bhi[160][40], Blo[160][40];
    const int tid = threadIdx.x;
    const int lane = tid & 63, wid = tid >> 6;
    const int wm = wid & 1, wn = wid >> 1;
    const int rb = blockIdx.x * 64;

    // A staging coords (fixed per thread): 8 contiguous k per thread
    const int rl = tid >> 2, kk = (tid & 3) << 3;
    const int arow = rb + rl;
    const int ab = arow / 144, ahh = arow - ab * 144;
    int fl = 0, pa = 0;
    if (PATCH) { fl = *flag; if (fl) pa = amax[arow]; }

    // B staging coords
    const int br0 = tid >> 2, bk0 = (tid & 3) << 3;          // rows 0..63
    const int br2 = 128 + (tid >> 3), bk2 = (tid & 7) << 2;  // rows 128..159

    float av[8];
    short8v vbh0, vbl0, vbh1, vbl1;
    ushort vbh2[4], vbl2[4];

    auto LOAD = [&](int kb) {
        int k1 = kb + kk, c1 = k1 / 144, w1 = k1 - c1 * 144;
        const float4 t0 = *reinterpret_cast<const float4*>(
            x + (((size_t)(ab * 8 + c1) * 144 + ahh) * 144 + w1));
        int k2 = k1 + 4, c2 = k2 / 144, w2 = k2 - c2 * 144;
        const float4 t1 = *reinterpret_cast<const float4*>(
            x + (((size_t)(ab * 8 + c2) * 144 + ahh) * 144 + w2));
        av[0] = t0.x; av[1] = t0.y; av[2] = t0.z; av[3] = t0.w;
        av[4] = t1.x; av[5] = t1.y; av[6] = t1.z; av[7] = t1.w;
        if (PATCH && fl) {
            int d0 = w1 - pa + 2;
#pragma unroll
            for (int q = 0; q < 4; q++) {
                int dw = d0 + q;
                if (dw >= 0 && dw < 5)
                    av[q] = refined5[(size_t)ab * 5760 + (c1 * 144 + ahh) * 5 + dw];
            }
            int d1 = w2 - pa + 2;
#pragma unroll
            for (int q = 0; q < 4; q++) {
                int dw = d1 + q;
                if (dw >= 0 && dw < 5)
                    av[4 + q] = refined5[(size_t)ab * 5760 + (c2 * 144 + ahh) * 5 + dw];
            }
        }
        size_t o0 = (size_t)br0 * 1152 + kb + bk0;
        vbh0 = *reinterpret_cast<const short8v*>(Wchi + o0);
        vbl0 = *reinterpret_cast<const short8v*>(Wclo + o0);
        size_t o1 = (size_t)(br0 + 64) * 1152 + kb + bk0;
        vbh1 = *reinterpret_cast<const short8v*>(Wchi + o1);
        vbl1 = *reinterpret_cast<const short8v*>(Wclo + o1);
        size_t o2 = (size_t)br2 * 1152 + kb + bk2;
#pragma unroll
        for (int q = 0; q < 4; q++) { vbh2[q] = Wchi[o2 + q]; vbl2[q] = Wclo[o2 + q]; }
    };

    auto STORE = [&]() {
        ushort h[8], l[8];
#pragma unroll
        for (int q = 0; q < 8; q++) {
            h[q] = f2bf(av[q]);
            l[q] = f2bf(av[q] - bf2f(h[q]));
        }
#pragma unroll
        for (int q = 0; q < 8; q++) { Ahi[rl][kk + q] = h[q]; Alo[rl][kk + q] = l[q]; }
        *reinterpret_cast<short8v*>(&Bhi[br0][bk0]) = vbh0;
        *reinterpret_cast<short8v*>(&Blo[br0][bk0]) = vbl0;
        *reinterpret_cast<short8v*>(&Bhi[br0 + 64][bk0]) = vbh1;
        *reinterpret_cast<short8v*>(&Blo[br0 + 64][bk0]) = vbl1;
#pragma unroll
        for (int q = 0; q < 4; q++) { Bhi[br2][bk2 + q] = vbh2[q]; Blo[br2][bk2 + q] = vbl2[q]; }
    };

    f32x4 acc[2][5];
#pragma unroll
    for (int mt = 0; mt < 2; mt++)
#pragma unroll
        for (int nt = 0; nt < 5; nt++) acc[mt][nt] = (f32x4){0.f, 0.f, 0.f, 0.f};

    const int fr = lane & 15, fg = (lane >> 4) << 3;

    LOAD(0);
    for (int t = 0; t < 36; t++) {
        STORE();
        if (t < 35) LOAD((t + 1) * 32);
        __syncthreads();
        short8v ah0 = *reinterpret_cast<const short8v*>(&Ahi[wm * 32 + fr][fg]);
        short8v al0 = *reinterpret_cast<const short8v*>(&Alo[wm * 32 + fr][fg]);
        short8v ah1 = *reinterpret_cast<const short8v*>(&Ahi[wm * 32 + 16 + fr][fg]);
        short8v al1 = *reinterpret_cast<const short8v*>(&Alo[wm * 32 + 16 + fr][fg]);
#pragma unroll
        for (int nt = 0; nt < 5; nt++) {
            short8v bh = *reinterpret_cast<const short8v*>(&Bhi[wn * 80 + nt * 16 + fr][fg]);
            short8v bl = *reinterpret_cast<const short8v*>(&Blo[wn * 80 + nt * 16 + fr][fg]);
            acc[0][nt] = __builtin_amdgcn_mfma_f32_16x16x32_bf16(ah0, bh, acc[0][nt], 0, 0, 0);
            acc[0][nt] = __builtin_amdgcn_mfma_f32_16x16x32_bf16(ah0, bl, acc[0][nt], 0, 0, 0);
            acc[0][nt] = __builtin_amdgcn_mfma_f32_16x16x32_bf16(al0, bh, acc[0][nt], 0, 0, 0);
            acc[1][nt] = __builtin_amdgcn_mfma_f32_16x16x32_bf16(ah1, bh, acc[1][nt], 0, 0, 0);
            acc[1][nt] = __builtin_amdgcn_mfma_f32_16x16x32_bf16(ah1, bl, acc[1][nt], 0, 0, 0);
            acc[1][nt] = __builtin_amdgcn_mfma_f32_16x16x32_bf16(al1, bh, acc[1][nt], 0, 0, 0);
        }
        __syncthreads();
    }

    // epilogue: C/D layout col=lane&15, row=(lane>>4)*4+i  [m89-verified]
#pragma unroll
    for (int mt = 0; mt < 2; mt++) {
#pragma unroll
        for (int nt = 0; nt < 5; nt++) {
            int gcol = wn * 80 + nt * 16 + fr;
            if (gcol < 146) {
                float cc = cconst[gcol];
                float* dst = logits + (size_t)(rb + wm * 32 + mt * 16 + ((lane >> 4) << 2)) * 160 + gcol;
#pragma unroll
                for (int i = 0; i < 4; i++)
                    dst[(size_t)i * 160] = acc[mt][nt][i] + cc;
            }
        }
    }
}

// ---------------------------------------------------------------------------
// merged softmax: cls over cols 0..143 (+argmax & top-2 gap -> candidate list),
// ext over cols 144..145.  One wave per row, 4 rows per block.
// ---------------------------------------------------------------------------
__global__ __launch_bounds__(256) void softmax_heads(
    const float* __restrict__ logits, float* __restrict__ out_cls, float* __restrict__ out_ext,
    int* __restrict__ amax, float* __restrict__ partials,
    int* __restrict__ cand_count, int* __restrict__ cand_list)
{
    __shared__ float ps[4];
    int row = blockIdx.x * 4 + (threadIdx.x >> 6);
    int lane = threadIdx.x & 63;
    const float* L = logits + (size_t)row * 160;
    float v0 = L[lane];
    float v1 = L[lane + 64];
    float v2 = (lane < 16) ? L[lane + 128] : -3.0e38f;
    // argmax (first-max tie rule) + top-2 values
    float m = v0; int mi = lane;
    if (v1 > m) { m = v1; mi = lane + 64; }
    if (v2 > m) { m = v2; mi = lane + 128; }
    float m1 = v0, m2 = -3.0e38f;
    if (v1 > m1) { m2 = m1; m1 = v1; } else m2 = v1;
    if (v2 > m1) { m2 = m1; m1 = v2; } else m2 = fmaxf(m2, v2);
#pragma unroll
    for (int off = 32; off; off >>= 1) {
        float om = __shfl_xor(m, off);
        int   oi = __shfl_xor(mi, off);
        if (om > m || (om == m && oi < mi)) { m = om; mi = oi; }
        float om1 = __shfl_xor(m1, off);
        float om2 = __shfl_xor(m2, off);
        float nm1 = fmaxf(m1, om1);
        m2 = fmaxf(fminf(m1, om1), fmaxf(m2, om2));
        m1 = nm1;
    }
    float e0 = expf(v0 - m), e1 = expf(v1 - m);
    float e2 = (lane < 16) ? expf(v2 - m) : 0.f;
    float s = e0 + e1 + e2;
#pragma unroll
    for (int off = 32; off; off >>= 1) s += __shfl_xor(s, off);
    float inv = 1.f / s;
    float* O = out_cls + (size_t)row * 144;
    O[lane] = e0 * inv;
    O[lane + 64] = e1 * inv;
    if (lane < 16) O[lane + 128] = e2 * inv;

    // ext head (2 logits)
    float l0 = L[144], l1 = L[145];
    float mx = fmaxf(l0, l1);
    float ee0 = expf(l0 - mx), ee1 = expf(l1 - mx);
    float einv = 1.f / (ee0 + ee1);
    float p0 = ee0 * einv;
    if (lane == 0) {
        out_ext[(size_t)row * 2] = p0;
        out_ext[(size_t)row * 2 + 1] = ee1 * einv;
        if (amax != nullptr) {
            amax[row] = mi;
            if (m1 - m2 < GAPTH) {
                int slot = atomicAdd(cand_count, 1);
                cand_list[slot] = row;
            }
        }
    }
    if (partials != nullptr) {
        if (lane == 0) ps[threadIdx.x >> 6] = p0;
        __syncthreads();
        if (threadIdx.x == 0) partials[blockIdx.x] = (ps[0] + ps[1]) + (ps[2] + ps[3]);
    }
}

__global__ __launch_bounds__(256) void reduce_flag(const float* __restrict__ partials, int n,
                                                   int* __restrict__ flag)
{
    __shared__ float sm[256];
    int tid = threadIdx.x;
    float s = 0.f;
    for (int i = tid; i < n; i += 256) s += partials[i];
    sm[tid] = s; __syncthreads();
    for (int off = 128; off; off >>= 1) {
        if (tid < off) sm[tid] += sm[tid + off];
        __syncthreads();
    }
    if (tid == 0) *flag = (sm[0] * (1.f / 18432.f) > 0.3f) ? 1 : 0;
}

// ---------------------------------------------------------------------------
// fixup over compacted candidate list: exact f32 two-stage recompute of argmax.
// Transposed weights -> per-k coalesced loads, thread-parallel dots.
// ---------------------------------------------------------------------------
__global__ __launch_bounds__(256) void fixup_list(
    const int* __restrict__ cand_count, const int* __restrict__ cand_list,
    const float* __restrict__ x,
    const float* __restrict__ w1cT, const float* __restrict__ b1c,
    const float* __restrict__ gc, const float* __restrict__ bbc,
    const float* __restrict__ mc, const float* __restrict__ vc,
    const float* __restrict__ w2cT, const float* __restrict__ b2c,
    int* __restrict__ amax)
{
    __shared__ float xrow[1152];
    __shared__ float hsh[256];
    __shared__ float Lsh[144];
    const int tid = threadIdx.x;
    const int n = *cand_count;

    for (int ci = blockIdx.x; ci < n; ci += gridDim.x) {
        const int row = cand_list[ci];
        const int b = row / 144, hh = row - b * 144;
        for (int e = tid; e < 1152; e += 256) {
            int c = e / 144, w = e - c * 144;
            xrow[e] = x[(((size_t)(b * 8 + c) * 144 + hh) * 144) + w];
        }
        __syncthreads();
        // stage 1: thread tid owns output o=tid; w1cT[k][o] coalesced across threads
        {
            float a = 0.f;
#pragma unroll 8
            for (int k = 0; k < 1152; k++) a += w1cT[(size_t)k * 256 + tid] * xrow[k];
            float sc = gc[tid] * rsqrtf(vc[tid] + EPSF);
            hsh[tid] = (a + b1c[tid] - mc[tid]) * sc + bbc[tid];
        }
        __syncthreads();
        // stage 2: thread j<144 owns logit j; w2cT[k][j] coalesced
        if (tid < 144) {
            float a = 0.f;
#pragma unroll 8
            for (int k = 0; k < 256; k++) a += w2cT[(size_t)k * 144 + tid] * hsh[k];
            Lsh[tid] = a + b2c[tid];
        }
        __syncthreads();
        if (tid == 0) {
            int bi = 0; float bv = Lsh[0];
            for (int j = 1; j < 144; j++) if (Lsh[j] > bv) { bv = Lsh[j]; bi = j; }
            amax[row] = bi;
        }
        __syncthreads();
    }
}

// ---------------------------------------------------------------------------
// gather patches from zero-padded x at argmax windows
// ---------------------------------------------------------------------------
__global__ __launch_bounds__(256) void gather_patches(const float* __restrict__ x,
    const int* __restrict__ amax, float* __restrict__ patches)
{
    int idx = blockIdx.x * 256 + threadIdx.x;
    int b = idx / 5760, j = idx - b * 5760;
    int c = j / 720, r2 = j - c * 720;
    int hh = r2 / 5, tw = r2 - hh * 5;
    int a = amax[b * 144 + hh];
    int w = a + tw - 2;
    patches[idx] = (w >= 0 && w < 144) ? x[(((size_t)(b * 8 + c) * 144 + hh) * 144) + w] : 0.f;
}

// ---------------------------------------------------------------------------
// tok GEMM, K-split into 8 chunks of 720 (deterministic 2-stage)
// ---------------------------------------------------------------------------
__global__ __launch_bounds__(256) void tok_partial(const float* __restrict__ patches,
    const float* __restrict__ tok_w, float* __restrict__ tpart)
{
    __shared__ float P[720];
    int b = blockIdx.x, ks = blockIdx.y, tid = threadIdx.x;
    for (int e = tid; e < 720; e += 256) P[e] = patches[(size_t)b * 5760 + ks * 720 + e];
    __syncthreads();
    float acc = 0.f;
    const float* wbase = tok_w + (size_t)ks * 720 * 256;
    for (int k = 0; k < 720; k++) acc += P[k] * wbase[(size_t)k * 256 + tid];
    tpart[((size_t)b * 8 + ks) * 256 + tid] = acc;
}

// ---------------------------------------------------------------------------
// attn_front: tok_finish + LN1(x6) + qkv (q only for token 5) + attention row 5
// + out-proj token 5 + residual + LN2.  One block per batch elem, 512 threads.
// ---------------------------------------------------------------------------
__global__ __launch_bounds__(512) void attn_front(
    const float* __restrict__ tpart, const float* __restrict__ tok_b,
    const float* __restrict__ emb,
    const float* __restrict__ ln1_g, const float* __restrict__ ln1_b,
    const float* __restrict__ qkv_w,
    const float* __restrict__ out_w, const float* __restrict__ out_b,
    const float* __restrict__ ln2_g, const float* __restrict__ ln2_b,
    float* __restrict__ z2_5, float* __restrict__ t5out)
{
    __shared__ float s[256];
    __shared__ float z[6][256];
    __shared__ float qk[6][192];   // cols: 0-63 q (row5 only), 64-127 k, 128-191 v
    __shared__ float att[2][6];
    __shared__ float o5[64];
    __shared__ float t5[256];
    __shared__ float stat[2];
    const int b = blockIdx.x, tid = threadIdx.x;
    const int lane = tid & 63, wv = tid >> 6;

    if (tid < 256) {
        float a = tok_b[tid];
        for (int ks = 0; ks < 8; ks++) a += tpart[((size_t)b * 8 + ks) * 256 + tid];
        s[tid] = a;
    }
    __syncthreads();

    // LN1: wave wv handles token wv (wv<6)
    if (wv < 6) {
        float y[4], s1 = 0.f, s2 = 0.f;
#pragma unroll
        for (int q = 0; q < 4; q++) {
            int k = lane + 64 * q;
            y[q] = s[k] + emb[wv * 256 + k];
            s1 += y[q]; s2 += y[q] * y[q];
        }
#pragma unroll
        for (int off = 32; off; off >>= 1) { s1 += __shfl_xor(s1, off); s2 += __shfl_xor(s2, off); }
        float mu = s1 * (1.f / 256.f);
        float var = s2 * (1.f / 256.f) - mu * mu;
        float rs = rsqrtf(var + EPSF);
#pragma unroll
        for (int q = 0; q < 4; q++) {
            int k = lane + 64 * q;
            z[wv][k] = (y[q] - mu) * rs * ln1_g[k] + ln1_b[k];
        }
    }
    __syncthreads();

    // qkv dots: d<768 -> k/v for token i=d>>7, col c=64+(d&127); d>=768 -> q5, c=d-768
    for (int d = tid; d < 832; d += 512) {
        int i, c;
        if (d < 768) { i = d >> 7; c = 64 + (d & 127); }
        else         { i = 5;      c = d - 768; }
        float a = 0.f;
#pragma unroll 4
        for (int k = 0; k < 256; k++) a += z[i][k] * qkv_w[(size_t)k * 192 + c];
        qk[i][c] = a;
    }
    __syncthreads();

    // attention row 5 only
    if (tid < 12) {
        int h = tid / 6, j = tid - h * 6;
        float a = 0.f;
#pragma unroll
        for (int d = 0; d < 32; d++) a += qk[5][h * 32 + d] * qk[j][64 + h * 32 + d];
        att[h][j] = a * 0.17677669529663687f;
    }
    __syncthreads();
    if (tid < 2) {
        float m = -3.0e38f;
        for (int j = 0; j < 6; j++) m = fmaxf(m, att[tid][j]);
        float ssum = 0.f;
        for (int j = 0; j < 6; j++) { float e = expf(att[tid][j] - m); att[tid][j] = e; ssum += e; }
        float inv = 1.f / ssum;
        for (int j = 0; j < 6; j++) att[tid][j] *= inv;
    }
    __syncthreads();
    if (tid < 64) {
        int h = tid >> 5;
        float a = 0.f;
#pragma unroll
        for (int j = 0; j < 6; j++) a += att[h][j] * qk[j][128 + tid];
        o5[tid] = a;
    }
    __syncthreads();

    // out-proj token 5 + residual
    if (tid < 256) {
        float a = out_b[tid] + s[tid] + emb[5 * 256 + tid];
#pragma unroll 4
        for (int d = 0; d < 64; d++) a += o5[d] * out_w[(size_t)d * 256 + tid];
        t5[tid] = a;
    }
    __syncthreads();

    // LN2 stats (wave 0)
    if (wv == 0) {
        float s1 = 0.f, s2 = 0.f;
#pragma unroll
        for (int q = 0; q < 4; q++) { float vv = t5[lane + 64 * q]; s1 += vv; s2 += vv * vv; }
#pragma unroll
        for (int off = 32; off; off >>= 1) { s1 += __shfl_xor(s1, off); s2 += __shfl_xor(s2, off); }
        if (lane == 0) {
            float mu = s1 * (1.f / 256.f);
            float var = s2 * (1.f / 256.f) - mu * mu;
            stat[0] = mu; stat[1] = rsqrtf(var + EPSF);
        }
    }
    __syncthreads();
    if (tid < 256) {
        t5out[(size_t)b * 256 + tid] = t5[tid];
        z2_5[(size_t)b * 256 + tid] = (t5[tid] - stat[0]) * stat[1] * ln2_g[tid] + ln2_b[tid];
    }
}

// ---------------------------------------------------------------------------
// ff1 + exact gelu for token 5: f5[b, jj] over N=512 split in 2 blocks
// ---------------------------------------------------------------------------
__global__ __launch_bounds__(256) void ff1_gelu(
    const float* __restrict__ z2_5, const float* __restrict__ ff_w1,
    const float* __restrict__ ff_b1, float* __restrict__ f5)
{
    __shared__ float zsh[256];
    const int b = blockIdx.x, half = blockIdx.y, tid = threadIdx.x;
    zsh[tid] = z2_5[(size_t)b * 256 + tid];
    __syncthreads();
    const int jj = half * 256 + tid;
    float a = ff_b1[jj];
#pragma unroll 4
    for (int k = 0; k < 256; k++) a += zsh[k] * ff_w1[(size_t)k * 512 + jj];
    f5[(size_t)b * 512 + jj] = 0.5f * a * (1.f + erff(a * 0.70710678118654752f));
}

// ---------------------------------------------------------------------------
// ff2 + residual + LNF for token 5 -> tfin
// ---------------------------------------------------------------------------
__global__ __launch_bounds__(256) void ff2_lnf(
    const float* __restrict__ f5, const float* __restrict__ ff_w2,
    const float* __restrict__ ff_b2, const float* __restrict__ t5in,
    const float* __restrict__ lnf_g, const float* __restrict__ lnf_b,
    float* __restrict__ tfin)
{
    __shared__ float fsh[512];
    __shared__ float tsh[256];
    __shared__ float stat[2];
    const int b = blockIdx.x, tid = threadIdx.x;
    const int lane = tid & 63;
    fsh[tid] = f5[(size_t)b * 512 + tid];
    fsh[tid + 256] = f5[(size_t)b * 512 + tid + 256];
    __syncthreads();
    float a = ff_b2[tid] + t5in[(size_t)b * 256 + tid];
#pragma unroll 4
    for (int k = 0; k < 512; k++) a += fsh[k] * ff_w2[(size_t)k * 256 + tid];
    tsh[tid] = a;
    __syncthreads();
    if (tid < 64) {
        float s1 = 0.f, s2 = 0.f;
#pragma unroll
        for (int q = 0; q < 4; q++) { float vv = tsh[lane + 64 * q]; s1 += vv; s2 += vv * vv; }
#pragma unroll
        for (int off = 32; off; off >>= 1) { s1 += __shfl_xor(s1, off); s2 += __shfl_xor(s2, off); }
        if (lane == 0) {
            float mu = s1 * (1.f / 256.f);
            float var = s2 * (1.f / 256.f) - mu * mu;
            stat[0] = mu; stat[1] = rsqrtf(var + EPSF);
        }
    }
    __syncthreads();
    tfin[(size_t)b * 256 + tid] = (tsh[tid] - stat[0]) * stat[1] * lnf_g[tid] + lnf_b[tid];
}

// ---------------------------------------------------------------------------
// fin GEMM for token 5: refined5[b,n] = tfin[b,:] @ fin_w[:,n] + fin_b[n]
// ---------------------------------------------------------------------------
__global__ __launch_bounds__(256) void fin_gemm(const float* __restrict__ tfin,
    const float* __restrict__ fin_w, const float* __restrict__ fin_b, float* __restrict__ refined5)
{
    __shared__ float tf[16][256];
    int tid = threadIdx.x;
    int nb = blockIdx.x * 256 + tid;
    int bg = blockIdx.y * 16;
    for (int e = tid; e < 4096; e += 256) tf[e >> 8][e & 255] = tfin[(size_t)(bg + (e >> 8)) * 256 + (e & 255)];
    __syncthreads();
    if (nb < 5760) {
        float acc[16];
#pragma unroll
        for (int bb = 0; bb < 16; bb++) acc[bb] = 0.f;
        for (int k = 0; k < 256; k++) {
            float wv = fin_w[(size_t)k * 5760 + nb];
#pragma unroll
            for (int bb = 0; bb < 16; bb++) acc[bb] += tf[bb][k] * wv;
        }
        float fb = fin_b[nb];
#pragma unroll
        for (int bb = 0; bb < 16; bb++)
            refined5[(size_t)(bg + bb) * 5760 + nb] = acc[bb] + fb;
    }
}

// ---------------------------------------------------------------------------
extern "C" void kernel_launch(void* const* d_in, const int* in_sizes, int n_in,
                              void* d_out, int out_size, void* d_ws, size_t ws_size,
                              hipStream_t stream)
{
    const float* x      = (const float*)d_in[0];
    const float* ext_w1 = (const float*)d_in[1];
    const float* ext_b1 = (const float*)d_in[2];
    const float* ext_g  = (const float*)d_in[3];
    const float* ext_bb = (const float*)d_in[4];
    const float* ext_m  = (const float*)d_in[5];
    const float* ext_v  = (const float*)d_in[6];
    const float* ext_w2 = (const float*)d_in[7];
    const float* ext_b2 = (const float*)d_in[8];
    const float* cls_w1 = (const float*)d_in[9];
    const float* cls_b1 = (const float*)d_in[10];
    const float* cls_g  = (const float*)d_in[11];
    const float* cls_bb = (const float*)d_in[12];
    const float* cls_m  = (const float*)d_in[13];
    const float* cls_v  = (const float*)d_in[14];
    const float* cls_w2 = (const float*)d_in[15];
    const float* cls_b2 = (const float*)d_in[16];
    const float* tok_w  = (const float*)d_in[17];
    const float* tok_b  = (const float*)d_in[18];
    const float* emb    = (const float*)d_in[19];
    const float* ln1_g  = (const float*)d_in[20];
    const float* ln1_b  = (const float*)d_in[21];
    const float* qkv_w  = (const float*)d_in[22];
    const float* out_w  = (const float*)d_in[23];
    const float* out_b  = (const float*)d_in[24];
    const float* ln2_g  = (const float*)d_in[25];
    const float* ln2_b  = (const float*)d_in[26];
    const float* ff_w1  = (const float*)d_in[27];
    const float* ff_b1  = (const float*)d_in[28];
    const float* ff_w2  = (const float*)d_in[29];
    const float* ff_b2  = (const float*)d_in[30];
    const float* lnf_g  = (const float*)d_in[31];
    const float* lnf_b  = (const float*)d_in[32];
    const float* fin_w  = (const float*)d_in[33];
    const float* fin_b  = (const float*)d_in[34];

    float* out = (float*)d_out;
    float* ws  = (float*)d_ws;

    // workspace layout (float offsets)
    float*  Wc32     = ws;                       // 160*1152 = 184320
    float*  cconst   = ws + 184320;              // 160
    ushort* Wchi     = (ushort*)(ws + 184480);   // 184320 ushorts
    ushort* Wclo     = (ushort*)(ws + 276640);   // 184320 ushorts
    float*  logits   = ws + 368800;              // 18432*160 = 2949120
    float*  partials = ws + 3317920;             // 4608
    float*  patches  = ws + 3322528;             // 737280
    float*  z2_5     = ws + 4059808;             // 32768
    float*  t5buf    = ws + 4092576;             // 32768
    float*  f5buf    = ws + 4125344;             // 65536
    float*  tfin     = ws + 4256416;             // 32768
    float*  refined5 = ws + 4289184;             // 737280
    float*  tpart    = ws + 5026464;             // 262144
    int*    amax     = (int*)(ws + 5288608);     // 18432
    int*    flag     = (int*)(ws + 5307040);     // 1
    int*    cand_cnt = (int*)(ws + 5307041);     // 1
    int*    cand_lst = (int*)(ws + 5307042);     // 18432 -> ends 5325474
    float*  w1cT     = ws + 5325476;             // 1152*256 = 294912
    float*  w2cT     = ws + 5620388;             // 256*144  = 36864

    // output offsets: ext | cls | ext2 | cls2
    float* out_ext  = out;
    float* out_cls  = out + 36864;
    float* out_ext2 = out + 2691072;
    float* out_cls2 = out + 2727936;

    dim3 blk(256);

    // combined weights + transposed fixup weights (independent of x)
    wcomb_build<<<160, blk, 0, stream>>>(
        ext_w1, ext_b1, ext_g, ext_bb, ext_m, ext_v, ext_w2, ext_b2,
        cls_w1, cls_b1, cls_g, cls_bb, cls_m, cls_v, cls_w2, cls_b2,
        Wc32, Wchi, Wclo, cconst);
    zero_counters<<<1, 1, 0, stream>>>(cand_cnt);
    transpose_w<<<dim3(36, 8), blk, 0, stream>>>(cls_w1, w1cT, 256, 1152);
    transpose_w<<<dim3(8, 5), blk, 0, stream>>>(cls_w2, w2cT, 144, 256);

    // pass 1
    logits_gemm<0><<<288, blk, 0, stream>>>(x, Wchi, Wclo, cconst,
        nullptr, nullptr, nullptr, logits);
    softmax_heads<<<4608, blk, 0, stream>>>(logits, out_cls, out_ext, amax, partials,
        cand_cnt, cand_lst);
    reduce_flag<<<1, blk, 0, stream>>>(partials, 4608, flag);
    fixup_list<<<256, blk, 0, stream>>>(cand_cnt, cand_lst, x,
        w1cT, cls_b1, cls_g, cls_bb, cls_m, cls_v, w2cT, cls_b2, amax);

    // refine chain (always computed; application predicated on flag)
    gather_patches<<<2880, blk, 0, stream>>>(x, amax, patches);
    tok_partial<<<dim3(128, 8), blk, 0, stream>>>(patches, tok_w, tpart);
    attn_front<<<128, dim3(512), 0, stream>>>(tpart, tok_b, emb, ln1_g, ln1_b, qkv_w,
        out_w, out_b, ln2_g, ln2_b, z2_5, t5buf);
    ff1_gelu<<<dim3(128, 2), blk, 0, stream>>>(z2_5, ff_w1, ff_b1, f5buf);
    ff2_lnf<<<128, blk, 0, stream>>>(f5buf, ff_w2, ff_b2, t5buf, lnf_g, lnf_b, tfin);
    fin_gemm<<<dim3(23, 8), blk, 0, stream>>>(tfin, fin_w, fin_b, refined5);

    // pass 2 (x2 patched on the fly)
    logits_gemm<1><<<288, blk, 0, stream>>>(x, Wchi, Wclo, cconst,
        amax, refined5, flag, logits);
    softmax_heads<<<4608, blk, 0, stream>>>(logits, out_cls2, out_ext2, nullptr, nullptr,
        nullptr, nullptr);
}

// Round 8
// 385.299 us; speedup vs baseline: 1.0951x; 1.0651x over previous
//
#include <hip/hip_runtime.h>
#include <math.h>

#define EPSF 1e-5f
#define GAPTH 1e-3f
#define NKS 3           // K-split slices for logits GEMM
#define RROWS 18432

// B=128, C=8, H=144, W=144, CW=1152, R=18432, TW=5, OG=2, NCLS=6, DT=256, ITC=5760
// Collapsed head: logits[row, j] = sum_k Wc[j,k] * x'[row,k] + cconst[j]
//   j 0..143 = cls, j 144..145 = ext, j 146..159 = zero pad. NP=160.

typedef __attribute__((ext_vector_type(8))) short short8v;
typedef __attribute__((ext_vector_type(4))) float f32x4;
typedef unsigned short ushort;
typedef unsigned int uint;

__device__ inline ushort f2bf(float f) {
    uint u = __float_as_uint(f);
    uint r = (u + 0x7FFFu + ((u >> 16) & 1u)) >> 16;
    return (ushort)r;
}
__device__ inline float bf2f(ushort h) { return __uint_as_float(((uint)h) << 16); }

// ---------------------------------------------------------------------------
// Build combined weights: Wc[j,k] = sum_o w2[j,o]*s[o]*w1[o,k], s = g*rsqrt(v+eps)
// cconst[j] = sum_o w2[j,o]*((b1[o]-m[o])*s[o]+bb[o]) + b2[j].  Also bf16 hi/lo.
// ---------------------------------------------------------------------------
__global__ __launch_bounds__(256) void wcomb_build(
    const float* __restrict__ w1e, const float* __restrict__ b1e, const float* __restrict__ ge,
    const float* __restrict__ bbe, const float* __restrict__ me, const float* __restrict__ ve,
    const float* __restrict__ w2e, const float* __restrict__ b2e,
    const float* __restrict__ w1c, const float* __restrict__ b1c, const float* __restrict__ gc,
    const float* __restrict__ bbc, const float* __restrict__ mc, const float* __restrict__ vc,
    const float* __restrict__ w2c, const float* __restrict__ b2c,
    float* __restrict__ Wc32, ushort* __restrict__ Wchi, ushort* __restrict__ Wclo,
    float* __restrict__ cconst)
{
    __shared__ float coef[256];
    __shared__ float csum[4];
    const int j = blockIdx.x, tid = threadIdx.x;
    const int lane = tid & 63, wid = tid >> 6;

    const float *w1 = nullptr, *w2row = nullptr, *b1 = nullptr, *g = nullptr,
                *bb = nullptr, *m = nullptr, *v = nullptr;
    float b2v = 0.f;
    int valid = 0;
    if (j < 144) {
        valid = 1; w1 = w1c; w2row = w2c + (size_t)j * 256;
        b1 = b1c; g = gc; bb = bbc; m = mc; v = vc; b2v = b2c[j];
    } else if (j < 146) {
        valid = 1; w1 = w1e; w2row = w2e + (size_t)(j - 144) * 256;
        b1 = b1e; g = ge; bb = bbe; m = me; v = ve; b2v = b2e[j - 144];
    }

    float cf = 0.f, cc = 0.f;
    if (valid) {
        float s = g[tid] * rsqrtf(v[tid] + EPSF);
        float w2v = w2row[tid];
        cf = w2v * s;
        cc = w2v * ((b1[tid] - m[tid]) * s + bb[tid]);
    }
    coef[tid] = cf;
    float t = cc;
#pragma unroll
    for (int off = 32; off; off >>= 1) t += __shfl_xor(t, off);
    if (lane == 0) csum[wid] = t;
    __syncthreads();
    if (tid == 0) cconst[j] = valid ? ((csum[0] + csum[1]) + (csum[2] + csum[3]) + b2v) : 0.f;

    for (int k = tid; k < 1152; k += 256) {
        float acc = 0.f;
        if (valid) {
            for (int o = 0; o < 256; o++) acc += coef[o] * w1[(size_t)o * 1152 + k];
        }
        Wc32[(size_t)j * 1152 + k] = acc;
        ushort hi = f2bf(acc);
        Wchi[(size_t)j * 1152 + k] = hi;
        Wclo[(size_t)j * 1152 + k] = f2bf(acc - bf2f(hi));
    }
}

__global__ void zero_counters(int* __restrict__ cand_count)
{
    *cand_count = 0;
}

// ---------------------------------------------------------------------------
// tiled transpose: src[R][Cc] -> dst[Cc][R]
// ---------------------------------------------------------------------------
__global__ __launch_bounds__(256) void transpose_w(
    const float* __restrict__ src, float* __restrict__ dst, int R, int Cc)
{
    __shared__ float tile[32][33];
    const int rb = blockIdx.y * 32, cb = blockIdx.x * 32;
    const int tx = threadIdx.x & 31, ty = threadIdx.x >> 5;   // ty 0..7
#pragma unroll
    for (int i = ty; i < 32; i += 8) {
        int r = rb + i, c = cb + tx;
        tile[i][tx] = (r < R && c < Cc) ? src[(size_t)r * Cc + c] : 0.f;
    }
    __syncthreads();
#pragma unroll
    for (int i = ty; i < 32; i += 8) {
        int c = cb + i, r = rb + tx;
        if (c < Cc && r < R) dst[(size_t)c * R + r] = tile[tx][i];
    }
}

// ---------------------------------------------------------------------------
// logits GEMM: M=18432, N=160(146 used), K=1152 split into NKS slices of 384.
// Split-bf16 MFMA (hi/lo, 3 products). BM=64, BN=160, BK=32; 4 waves 2m x 2n.
// Writes per-slice partials (no cconst); softmax sums slices.
// PATCH=1: x columns in argmax window replaced by refined5 (predicated on *flag)
// ---------------------------------------------------------------------------
template<int PATCH>
__global__ __launch_bounds__(256) void logits_gemm(
    const float* __restrict__ x, const ushort* __restrict__ Wchi, const ushort* __restrict__ Wclo,
    const int* __restrict__ amax,
    const float* __restrict__ refined5, const int* __restrict__ flag,
    float* __restrict__ logits_part)
{
    __shared__ ushort Ahi[64][40], Alo[64][40], Bhi[160][40], Blo[160][40];
    const int tid = threadIdx.x;
    const int lane = tid & 63, wid = tid >> 6;
    const int wm = wid & 1, wn = wid >> 1;
    const int rb = blockIdx.x * 64;
    const int ks = blockIdx.y;
    const int kbase = ks * (1152 / NKS);        // 384 per slice
    const int NIT = (1152 / NKS) / 32;          // 12

    // A staging coords (fixed per thread): 8 contiguous k per thread
    const int rl = tid >> 2, kk = (tid & 3) << 3;
    const int arow = rb + rl;
    const int ab = arow / 144, ahh = arow - ab * 144;
    int fl = 0, pa = 0;
    if (PATCH) { fl = *flag; if (fl) pa = amax[arow]; }

    // B staging coords
    const int br0 = tid >> 2, bk0 = (tid & 3) << 3;          // rows 0..63 (+64..127)
    const int br2 = 128 + (tid >> 2), bk2 = (tid & 3) << 3;  // rows 128..159 (tid<128)

    float av[8];
    short8v vbh0, vbl0, vbh1, vbl1, vbh2, vbl2;

    auto LOAD = [&](int kb) {
        int k1 = kb + kk, c1 = k1 / 144, w1 = k1 - c1 * 144;
        const float4 t0 = *reinterpret_cast<const float4*>(
            x + (((size_t)(ab * 8 + c1) * 144 + ahh) * 144 + w1));
        int k2 = k1 + 4, c2 = k2 / 144, w2 = k2 - c2 * 144;
        const float4 t1 = *reinterpret_cast<const float4*>(
            x + (((size_t)(ab * 8 + c2) * 144 + ahh) * 144 + w2));
        av[0] = t0.x; av[1] = t0.y; av[2] = t0.z; av[3] = t0.w;
        av[4] = t1.x; av[5] = t1.y; av[6] = t1.z; av[7] = t1.w;
        if (PATCH && fl) {
            int d0 = w1 - pa + 2;
#pragma unroll
            for (int q = 0; q < 4; q++) {
                int dw = d0 + q;
                if (dw >= 0 && dw < 5)
                    av[q] = refined5[(size_t)ab * 5760 + (c1 * 144 + ahh) * 5 + dw];
            }
            int d1 = w2 - pa + 2;
#pragma unroll
            for (int q = 0; q < 4; q++) {
                int dw = d1 + q;
                if (dw >= 0 && dw < 5)
                    av[4 + q] = refined5[(size_t)ab * 5760 + (c2 * 144 + ahh) * 5 + dw];
            }
        }
        size_t o0 = (size_t)br0 * 1152 + kb + bk0;
        vbh0 = *reinterpret_cast<const short8v*>(Wchi + o0);
        vbl0 = *reinterpret_cast<const short8v*>(Wclo + o0);
        size_t o1 = (size_t)(br0 + 64) * 1152 + kb + bk0;
        vbh1 = *reinterpret_cast<const short8v*>(Wchi + o1);
        vbl1 = *reinterpret_cast<const short8v*>(Wclo + o1);
        if (tid < 128) {
            size_t o2 = (size_t)br2 * 1152 + kb + bk2;
            vbh2 = *reinterpret_cast<const short8v*>(Wchi + o2);
            vbl2 = *reinterpret_cast<const short8v*>(Wclo + o2);
        }
    };

    auto STORE = [&]() {
        short8v hv, lv;
#pragma unroll
        for (int q = 0; q < 8; q++) {
            ushort h = f2bf(av[q]);
            hv[q] = (short)h;
            lv[q] = (short)f2bf(av[q] - bf2f(h));
        }
        *reinterpret_cast<short8v*>(&Ahi[rl][kk]) = hv;
        *reinterpret_cast<short8v*>(&Alo[rl][kk]) = lv;
        *reinterpret_cast<short8v*>(&Bhi[br0][bk0]) = vbh0;
        *reinterpret_cast<short8v*>(&Blo[br0][bk0]) = vbl0;
        *reinterpret_cast<short8v*>(&Bhi[br0 + 64][bk0]) = vbh1;
        *reinterpret_cast<short8v*>(&Blo[br0 + 64][bk0]) = vbl1;
        if (tid < 128) {
            *reinterpret_cast<short8v*>(&Bhi[br2][bk2]) = vbh2;
            *reinterpret_cast<short8v*>(&Blo[br2][bk2]) = vbl2;
        }
    };

    f32x4 acc[2][5];
#pragma unroll
    for (int mt = 0; mt < 2; mt++)
#pragma unroll
        for (int nt = 0; nt < 5; nt++) acc[mt][nt] = (f32x4){0.f, 0.f, 0.f, 0.f};

    const int fr = lane & 15, fg = (lane >> 4) << 3;

    LOAD(kbase);
    for (int t = 0; t < NIT; t++) {
        STORE();
        if (t < NIT - 1) LOAD(kbase + (t + 1) * 32);
        __syncthreads();
        short8v ah0 = *reinterpret_cast<const short8v*>(&Ahi[wm * 32 + fr][fg]);
        short8v al0 = *reinterpret_cast<const short8v*>(&Alo[wm * 32 + fr][fg]);
        short8v ah1 = *reinterpret_cast<const short8v*>(&Ahi[wm * 32 + 16 + fr][fg]);
        short8v al1 = *reinterpret_cast<const short8v*>(&Alo[wm * 32 + 16 + fr][fg]);
#pragma unroll
        for (int nt = 0; nt < 5; nt++) {
            short8v bh = *reinterpret_cast<const short8v*>(&Bhi[wn * 80 + nt * 16 + fr][fg]);
            short8v bl = *reinterpret_cast<const short8v*>(&Blo[wn * 80 + nt * 16 + fr][fg]);
            acc[0][nt] = __builtin_amdgcn_mfma_f32_16x16x32_bf16(ah0, bh, acc[0][nt], 0, 0, 0);
            acc[0][nt] = __builtin_amdgcn_mfma_f32_16x16x32_bf16(ah0, bl, acc[0][nt], 0, 0, 0);
            acc[0][nt] = __builtin_amdgcn_mfma_f32_16x16x32_bf16(al0, bh, acc[0][nt], 0, 0, 0);
            acc[1][nt] = __builtin_amdgcn_mfma_f32_16x16x32_bf16(ah1, bh, acc[1][nt], 0, 0, 0);
            acc[1][nt] = __builtin_amdgcn_mfma_f32_16x16x32_bf16(ah1, bl, acc[1][nt], 0, 0, 0);
            acc[1][nt] = __builtin_amdgcn_mfma_f32_16x16x32_bf16(al1, bh, acc[1][nt], 0, 0, 0);
        }
        __syncthreads();
    }

    // epilogue: C/D layout col=lane&15, row=(lane>>4)*4+i  [m89-verified]
    float* base = logits_part + (size_t)ks * RROWS * 160;
#pragma unroll
    for (int mt = 0; mt < 2; mt++) {
#pragma unroll
        for (int nt = 0; nt < 5; nt++) {
            int gcol = wn * 80 + nt * 16 + fr;
            if (gcol < 146) {
                float* dst = base + (size_t)(rb + wm * 32 + mt * 16 + ((lane >> 4) << 2)) * 160 + gcol;
#pragma unroll
                for (int i = 0; i < 4; i++)
                    dst[(size_t)i * 160] = acc[mt][nt][i];
            }
        }
    }
}

// ---------------------------------------------------------------------------
// merged softmax over summed K-slices: cls cols 0..143 (+argmax & gap->cands),
// ext cols 144..145.  One wave per row, 4 rows per block.
// ---------------------------------------------------------------------------
__global__ __launch_bounds__(256) void softmax_heads(
    const float* __restrict__ logits_part, const float* __restrict__ cconst,
    float* __restrict__ out_cls, float* __restrict__ out_ext,
    int* __restrict__ amax, float* __restrict__ partials,
    int* __restrict__ cand_count, int* __restrict__ cand_list)
{
    __shared__ float ps[4];
    int row = blockIdx.x * 4 + (threadIdx.x >> 6);
    int lane = threadIdx.x & 63;
    const float* L0 = logits_part + (size_t)row * 160;
    const float* L1 = L0 + (size_t)RROWS * 160;
    const float* L2 = L1 + (size_t)RROWS * 160;
    float v0 = L0[lane] + L1[lane] + L2[lane] + cconst[lane];
    float v1 = L0[lane + 64] + L1[lane + 64] + L2[lane + 64] + cconst[lane + 64];
    float v2 = (lane < 16) ? (L0[lane + 128] + L1[lane + 128] + L2[lane + 128] + cconst[lane + 128])
                           : -3.0e38f;
    // argmax (first-max tie rule) + top-2 values
    float m = v0; int mi = lane;
    if (v1 > m) { m = v1; mi = lane + 64; }
    if (v2 > m) { m = v2; mi = lane + 128; }
    float m1 = v0, m2 = -3.0e38f;
    if (v1 > m1) { m2 = m1; m1 = v1; } else m2 = v1;
    if (v2 > m1) { m2 = m1; m1 = v2; } else m2 = fmaxf(m2, v2);
#pragma unroll
    for (int off = 32; off; off >>= 1) {
        float om = __shfl_xor(m, off);
        int   oi = __shfl_xor(mi, off);
        if (om > m || (om == m && oi < mi)) { m = om; mi = oi; }
        float om1 = __shfl_xor(m1, off);
        float om2 = __shfl_xor(m2, off);
        float nm1 = fmaxf(m1, om1);
        m2 = fmaxf(fminf(m1, om1), fmaxf(m2, om2));
        m1 = nm1;
    }
    float e0 = expf(v0 - m), e1 = expf(v1 - m);
    float e2 = (lane < 16) ? expf(v2 - m) : 0.f;
    float s = e0 + e1 + e2;
#pragma unroll
    for (int off = 32; off; off >>= 1) s += __shfl_xor(s, off);
    float inv = 1.f / s;
    float* O = out_cls + (size_t)row * 144;
    O[lane] = e0 * inv;
    O[lane + 64] = e1 * inv;
    if (lane < 16) O[lane + 128] = e2 * inv;

    // ext head (2 logits)
    float l0 = L0[144] + L1[144] + L2[144] + cconst[144];
    float l1 = L0[145] + L1[145] + L2[145] + cconst[145];
    float mx = fmaxf(l0, l1);
    float ee0 = expf(l0 - mx), ee1 = expf(l1 - mx);
    float einv = 1.f / (ee0 + ee1);
    float p0 = ee0 * einv;
    if (lane == 0) {
        out_ext[(size_t)row * 2] = p0;
        out_ext[(size_t)row * 2 + 1] = ee1 * einv;
        if (amax != nullptr) {
            amax[row] = mi;
            if (m1 - m2 < GAPTH) {
                int slot = atomicAdd(cand_count, 1);
                cand_list[slot] = row;
            }
        }
    }
    if (partials != nullptr) {
        if (lane == 0) ps[threadIdx.x >> 6] = p0;
        __syncthreads();
        if (threadIdx.x == 0) partials[blockIdx.x] = (ps[0] + ps[1]) + (ps[2] + ps[3]);
    }
}

__global__ __launch_bounds__(256) void reduce_flag(const float* __restrict__ partials, int n,
                                                   int* __restrict__ flag)
{
    __shared__ float sm[256];
    int tid = threadIdx.x;
    float s = 0.f;
    for (int i = tid; i < n; i += 256) s += partials[i];
    sm[tid] = s; __syncthreads();
    for (int off = 128; off; off >>= 1) {
        if (tid < off) sm[tid] += sm[tid + off];
        __syncthreads();
    }
    if (tid == 0) *flag = (sm[0] * (1.f / 18432.f) > 0.3f) ? 1 : 0;
}

// ---------------------------------------------------------------------------
// fixup over compacted candidate list: exact f32 two-stage recompute of argmax.
// Transposed weights -> per-k coalesced loads, thread-parallel dots.
// ---------------------------------------------------------------------------
__global__ __launch_bounds__(256) void fixup_list(
    const int* __restrict__ cand_count, const int* __restrict__ cand_list,
    const float* __restrict__ x,
    const float* __restrict__ w1cT, const float* __restrict__ b1c,
    const float* __restrict__ gc, const float* __restrict__ bbc,
    const float* __restrict__ mc, const float* __restrict__ vc,
    const float* __restrict__ w2cT, const float* __restrict__ b2c,
    int* __restrict__ amax)
{
    __shared__ float xrow[1152];
    __shared__ float hsh[256];
    __shared__ float Lsh[144];
    const int tid = threadIdx.x;
    const int n = *cand_count;

    for (int ci = blockIdx.x; ci < n; ci += gridDim.x) {
        const int row = cand_list[ci];
        const int b = row / 144, hh = row - b * 144;
        for (int e = tid; e < 1152; e += 256) {
            int c = e / 144, w = e - c * 144;
            xrow[e] = x[(((size_t)(b * 8 + c) * 144 + hh) * 144) + w];
        }
        __syncthreads();
        // stage 1: thread tid owns output o=tid; w1cT[k][o] coalesced across threads
        {
            float a = 0.f;
#pragma unroll 8
            for (int k = 0; k < 1152; k++) a += w1cT[(size_t)k * 256 + tid] * xrow[k];
            float sc = gc[tid] * rsqrtf(vc[tid] + EPSF);
            hsh[tid] = (a + b1c[tid] - mc[tid]) * sc + bbc[tid];
        }
        __syncthreads();
        // stage 2: thread j<144 owns logit j; w2cT[k][j] coalesced
        if (tid < 144) {
            float a = 0.f;
#pragma unroll 8
            for (int k = 0; k < 256; k++) a += w2cT[(size_t)k * 144 + tid] * hsh[k];
            Lsh[tid] = a + b2c[tid];
        }
        __syncthreads();
        if (tid == 0) {
            int bi = 0; float bv = Lsh[0];
            for (int j = 1; j < 144; j++) if (Lsh[j] > bv) { bv = Lsh[j]; bi = j; }
            amax[row] = bi;
        }
        __syncthreads();
    }
}

// ---------------------------------------------------------------------------
// gather patches from zero-padded x at argmax windows
// ---------------------------------------------------------------------------
__global__ __launch_bounds__(256) void gather_patches(const float* __restrict__ x,
    const int* __restrict__ amax, float* __restrict__ patches)
{
    int idx = blockIdx.x * 256 + threadIdx.x;
    int b = idx / 5760, j = idx - b * 5760;
    int c = j / 720, r2 = j - c * 720;
    int hh = r2 / 5, tw = r2 - hh * 5;
    int a = amax[b * 144 + hh];
    int w = a + tw - 2;
    patches[idx] = (w >= 0 && w < 144) ? x[(((size_t)(b * 8 + c) * 144 + hh) * 144) + w] : 0.f;
}

// ---------------------------------------------------------------------------
// tok GEMM, K-split into 8 chunks of 720 (deterministic 2-stage)
// ---------------------------------------------------------------------------
__global__ __launch_bounds__(256) void tok_partial(const float* __restrict__ patches,
    const float* __restrict__ tok_w, float* __restrict__ tpart)
{
    __shared__ float P[720];
    int b = blockIdx.x, ks = blockIdx.y, tid = threadIdx.x;
    for (int e = tid; e < 720; e += 256) P[e] = patches[(size_t)b * 5760 + ks * 720 + e];
    __syncthreads();
    float acc = 0.f;
    const float* wbase = tok_w + (size_t)ks * 720 * 256;
    for (int k = 0; k < 720; k++) acc += P[k] * wbase[(size_t)k * 256 + tid];
    tpart[((size_t)b * 8 + ks) * 256 + tid] = acc;
}

// ---------------------------------------------------------------------------
// attn_front: tok_finish + LN1(x6) + qkv (q only for token 5) + attention row 5
// + out-proj token 5 + residual + LN2.  One block per batch elem, 512 threads.
// ---------------------------------------------------------------------------
__global__ __launch_bounds__(512) void attn_front(
    const float* __restrict__ tpart, const float* __restrict__ tok_b,
    const float* __restrict__ emb,
    const float* __restrict__ ln1_g, const float* __restrict__ ln1_b,
    const float* __restrict__ qkv_w,
    const float* __restrict__ out_w, const float* __restrict__ out_b,
    const float* __restrict__ ln2_g, const float* __restrict__ ln2_b,
    float* __restrict__ z2_5, float* __restrict__ t5out)
{
    __shared__ float s[256];
    __shared__ float z[6][256];
    __shared__ float qk[6][192];   // cols: 0-63 q (row5 only), 64-127 k, 128-191 v
    __shared__ float att[2][6];
    __shared__ float o5[64];
    __shared__ float t5[256];
    __shared__ float stat[2];
    const int b = blockIdx.x, tid = threadIdx.x;
    const int lane = tid & 63, wv = tid >> 6;

    if (tid < 256) {
        float a = tok_b[tid];
        for (int ks = 0; ks < 8; ks++) a += tpart[((size_t)b * 8 + ks) * 256 + tid];
        s[tid] = a;
    }
    __syncthreads();

    // LN1: wave wv handles token wv (wv<6)
    if (wv < 6) {
        float y[4], s1 = 0.f, s2 = 0.f;
#pragma unroll
        for (int q = 0; q < 4; q++) {
            int k = lane + 64 * q;
            y[q] = s[k] + emb[wv * 256 + k];
            s1 += y[q]; s2 += y[q] * y[q];
        }
#pragma unroll
        for (int off = 32; off; off >>= 1) { s1 += __shfl_xor(s1, off); s2 += __shfl_xor(s2, off); }
        float mu = s1 * (1.f / 256.f);
        float var = s2 * (1.f / 256.f) - mu * mu;
        float rs = rsqrtf(var + EPSF);
#pragma unroll
        for (int q = 0; q < 4; q++) {
            int k = lane + 64 * q;
            z[wv][k] = (y[q] - mu) * rs * ln1_g[k] + ln1_b[k];
        }
    }
    __syncthreads();

    // qkv dots: d<768 -> k/v for token i=d>>7, col c=64+(d&127); d>=768 -> q5, c=d-768
    for (int d = tid; d < 832; d += 512) {
        int i, c;
        if (d < 768) { i = d >> 7; c = 64 + (d & 127); }
        else         { i = 5;      c = d - 768; }
        float a = 0.f;
#pragma unroll 4
        for (int k = 0; k < 256; k++) a += z[i][k] * qkv_w[(size_t)k * 192 + c];
        qk[i][c] = a;
    }
    __syncthreads();

    // attention row 5 only
    if (tid < 12) {
        int h = tid / 6, j = tid - h * 6;
        float a = 0.f;
#pragma unroll
        for (int d = 0; d < 32; d++) a += qk[5][h * 32 + d] * qk[j][64 + h * 32 + d];
        att[h][j] = a * 0.17677669529663687f;
    }
    __syncthreads();
    if (tid < 2) {
        float m = -3.0e38f;
        for (int j = 0; j < 6; j++) m = fmaxf(m, att[tid][j]);
        float ssum = 0.f;
        for (int j = 0; j < 6; j++) { float e = expf(att[tid][j] - m); att[tid][j] = e; ssum += e; }
        float inv = 1.f / ssum;
        for (int j = 0; j < 6; j++) att[tid][j] *= inv;
    }
    __syncthreads();
    if (tid < 64) {
        int h = tid >> 5;
        float a = 0.f;
#pragma unroll
        for (int j = 0; j < 6; j++) a += att[h][j] * qk[j][128 + tid];
        o5[tid] = a;
    }
    __syncthreads();

    // out-proj token 5 + residual
    if (tid < 256) {
        float a = out_b[tid] + s[tid] + emb[5 * 256 + tid];
#pragma unroll 4
        for (int d = 0; d < 64; d++) a += o5[d] * out_w[(size_t)d * 256 + tid];
        t5[tid] = a;
    }
    __syncthreads();

    // LN2 stats (wave 0)
    if (wv == 0) {
        float s1 = 0.f, s2 = 0.f;
#pragma unroll
        for (int q = 0; q < 4; q++) { float vv = t5[lane + 64 * q]; s1 += vv; s2 += vv * vv; }
#pragma unroll
        for (int off = 32; off; off >>= 1) { s1 += __shfl_xor(s1, off); s2 += __shfl_xor(s2, off); }
        if (lane == 0) {
            float mu = s1 * (1.f / 256.f);
            float var = s2 * (1.f / 256.f) - mu * mu;
            stat[0] = mu; stat[1] = rsqrtf(var + EPSF);
        }
    }
    __syncthreads();
    if (tid < 256) {
        t5out[(size_t)b * 256 + tid] = t5[tid];
        z2_5[(size_t)b * 256 + tid] = (t5[tid] - stat[0]) * stat[1] * ln2_g[tid] + ln2_b[tid];
    }
}

// ---------------------------------------------------------------------------
// ff1 + exact gelu for token 5: f5[b, jj] over N=512 split in 2 blocks
// ---------------------------------------------------------------------------
__global__ __launch_bounds__(256) void ff1_gelu(
    const float* __restrict__ z2_5, const float* __restrict__ ff_w1,
    const float* __restrict__ ff_b1, float* __restrict__ f5)
{
    __shared__ float zsh[256];
    const int b = blockIdx.x, half = blockIdx.y, tid = threadIdx.x;
    zsh[tid] = z2_5[(size_t)b * 256 + tid];
    __syncthreads();
    const int jj = half * 256 + tid;
    float a = ff_b1[jj];
#pragma unroll 4
    for (int k = 0; k < 256; k++) a += zsh[k] * ff_w1[(size_t)k * 512 + jj];
    f5[(size_t)b * 512 + jj] = 0.5f * a * (1.f + erff(a * 0.70710678118654752f));
}

// ---------------------------------------------------------------------------
// ff2 + residual + LNF for token 5 -> tfin
// ---------------------------------------------------------------------------
__global__ __launch_bounds__(256) void ff2_lnf(
    const float* __restrict__ f5, const float* __restrict__ ff_w2,
    const float* __restrict__ ff_b2, const float* __restrict__ t5in,
    const float* __restrict__ lnf_g, const float* __restrict__ lnf_b,
    float* __restrict__ tfin)
{
    __shared__ float fsh[512];
    __shared__ float tsh[256];
    __shared__ float stat[2];
    const int b = blockIdx.x, tid = threadIdx.x;
    const int lane = tid & 63;
    fsh[tid] = f5[(size_t)b * 512 + tid];
    fsh[tid + 256] = f5[(size_t)b * 512 + tid + 256];
    __syncthreads();
    float a = ff_b2[tid] + t5in[(size_t)b * 256 + tid];
#pragma unroll 4
    for (int k = 0; k < 512; k++) a += fsh[k] * ff_w2[(size_t)k * 256 + tid];
    tsh[tid] = a;
    __syncthreads();
    if (tid < 64) {
        float s1 = 0.f, s2 = 0.f;
#pragma unroll
        for (int q = 0; q < 4; q++) { float vv = tsh[lane + 64 * q]; s1 += vv; s2 += vv * vv; }
#pragma unroll
        for (int off = 32; off; off >>= 1) { s1 += __shfl_xor(s1, off); s2 += __shfl_xor(s2, off); }
        if (lane == 0) {
            float mu = s1 * (1.f / 256.f);
            float var = s2 * (1.f / 256.f) - mu * mu;
            stat[0] = mu; stat[1] = rsqrtf(var + EPSF);
        }
    }
    __syncthreads();
    tfin[(size_t)b * 256 + tid] = (tsh[tid] - stat[0]) * stat[1] * lnf_g[tid] + lnf_b[tid];
}

// ---------------------------------------------------------------------------
// fin GEMM for token 5: refined5[b,n] = tfin[b,:] @ fin_w[:,n] + fin_b[n]
// ---------------------------------------------------------------------------
__global__ __launch_bounds__(256) void fin_gemm(const float* __restrict__ tfin,
    const float* __restrict__ fin_w, const float* __restrict__ fin_b, float* __restrict__ refined5)
{
    __shared__ float tf[16][256];
    int tid = threadIdx.x;
    int nb = blockIdx.x * 256 + tid;
    int bg = blockIdx.y * 16;
    for (int e = tid; e < 4096; e += 256) tf[e >> 8][e & 255] = tfin[(size_t)(bg + (e >> 8)) * 256 + (e & 255)];
    __syncthreads();
    if (nb < 5760) {
        float acc[16];
#pragma unroll
        for (int bb = 0; bb < 16; bb++) acc[bb] = 0.f;
        for (int k = 0; k < 256; k++) {
            float wv = fin_w[(size_t)k * 5760 + nb];
#pragma unroll
            for (int bb = 0; bb < 16; bb++) acc[bb] += tf[bb][k] * wv;
        }
        float fb = fin_b[nb];
#pragma unroll
        for (int bb = 0; bb < 16; bb++)
            refined5[(size_t)(bg + bb) * 5760 + nb] = acc[bb] + fb;
    }
}

// ---------------------------------------------------------------------------
extern "C" void kernel_launch(void* const* d_in, const int* in_sizes, int n_in,
                              void* d_out, int out_size, void* d_ws, size_t ws_size,
                              hipStream_t stream)
{
    const float* x      = (const float*)d_in[0];
    const float* ext_w1 = (const float*)d_in[1];
    const float* ext_b1 = (const float*)d_in[2];
    const float* ext_g  = (const float*)d_in[3];
    const float* ext_bb = (const float*)d_in[4];
    const float* ext_m  = (const float*)d_in[5];
    const float* ext_v  = (const float*)d_in[6];
    const float* ext_w2 = (const float*)d_in[7];
    const float* ext_b2 = (const float*)d_in[8];
    const float* cls_w1 = (const float*)d_in[9];
    const float* cls_b1 = (const float*)d_in[10];
    const float* cls_g  = (const float*)d_in[11];
    const float* cls_bb = (const float*)d_in[12];
    const float* cls_m  = (const float*)d_in[13];
    const float* cls_v  = (const float*)d_in[14];
    const float* cls_w2 = (const float*)d_in[15];
    const float* cls_b2 = (const float*)d_in[16];
    const float* tok_w  = (const float*)d_in[17];
    const float* tok_b  = (const float*)d_in[18];
    const float* emb    = (const float*)d_in[19];
    const float* ln1_g  = (const float*)d_in[20];
    const float* ln1_b  = (const float*)d_in[21];
    const float* qkv_w  = (const float*)d_in[22];
    const float* out_w  = (const float*)d_in[23];
    const float* out_b  = (const float*)d_in[24];
    const float* ln2_g  = (const float*)d_in[25];
    const float* ln2_b  = (const float*)d_in[26];
    const float* ff_w1  = (const float*)d_in[27];
    const float* ff_b1  = (const float*)d_in[28];
    const float* ff_w2  = (const float*)d_in[29];
    const float* ff_b2  = (const float*)d_in[30];
    const float* lnf_g  = (const float*)d_in[31];
    const float* lnf_b  = (const float*)d_in[32];
    const float* fin_w  = (const float*)d_in[33];
    const float* fin_b  = (const float*)d_in[34];

    float* out = (float*)d_out;
    float* ws  = (float*)d_ws;

    // workspace layout (float offsets)
    float*  Wc32     = ws;                        // 184320
    float*  cconst   = ws + 184320;               // 160
    ushort* Wchi     = (ushort*)(ws + 184480);    // 184320 ushorts (92160 floats)
    ushort* Wclo     = (ushort*)(ws + 276640);    // 92160 floats
    float*  logitsP  = ws + 368800;               // 3*18432*160 = 8847360
    float*  partials = ws + 9216160;              // 4608
    float*  patches  = ws + 9220768;              // 737280
    float*  z2_5     = ws + 9958048;              // 32768
    float*  t5buf    = ws + 9990816;              // 32768
    float*  f5buf    = ws + 10023584;             // 65536
    float*  tfin     = ws + 10089120;             // 32768
    float*  refined5 = ws + 10121888;             // 737280
    float*  tpart    = ws + 10859168;             // 262144
    int*    amax     = (int*)(ws + 11121312);     // 18432
    int*    flag     = (int*)(ws + 11139744);     // 1
    int*    cand_cnt = (int*)(ws + 11139745);     // 1
    int*    cand_lst = (int*)(ws + 11139746);     // 18432
    float*  w1cT     = ws + 11158180;             // 294912
    float*  w2cT     = ws + 11453092;             // 36864 -> ends 11489956

    // output offsets: ext | cls | ext2 | cls2
    float* out_ext  = out;
    float* out_cls  = out + 36864;
    float* out_ext2 = out + 2691072;
    float* out_cls2 = out + 2727936;

    dim3 blk(256);

    // combined weights + transposed fixup weights (independent of x)
    wcomb_build<<<160, blk, 0, stream>>>(
        ext_w1, ext_b1, ext_g, ext_bb, ext_m, ext_v, ext_w2, ext_b2,
        cls_w1, cls_b1, cls_g, cls_bb, cls_m, cls_v, cls_w2, cls_b2,
        Wc32, Wchi, Wclo, cconst);
    zero_counters<<<1, 1, 0, stream>>>(cand_cnt);
    transpose_w<<<dim3(36, 8), blk, 0, stream>>>(cls_w1, w1cT, 256, 1152);
    transpose_w<<<dim3(8, 5), blk, 0, stream>>>(cls_w2, w2cT, 144, 256);

    // pass 1
    logits_gemm<0><<<dim3(288, NKS), blk, 0, stream>>>(x, Wchi, Wclo,
        nullptr, nullptr, nullptr, logitsP);
    softmax_heads<<<4608, blk, 0, stream>>>(logitsP, cconst, out_cls, out_ext, amax, partials,
        cand_cnt, cand_lst);
    reduce_flag<<<1, blk, 0, stream>>>(partials, 4608, flag);
    fixup_list<<<256, blk, 0, stream>>>(cand_cnt, cand_lst, x,
        w1cT, cls_b1, cls_g, cls_bb, cls_m, cls_v, w2cT, cls_b2, amax);

    // refine chain (always computed; application predicated on flag)
    gather_patches<<<2880, blk, 0, stream>>>(x, amax, patches);
    tok_partial<<<dim3(128, 8), blk, 0, stream>>>(patches, tok_w, tpart);
    attn_front<<<128, dim3(512), 0, stream>>>(tpart, tok_b, emb, ln1_g, ln1_b, qkv_w,
        out_w, out_b, ln2_g, ln2_b, z2_5, t5buf);
    ff1_gelu<<<dim3(128, 2), blk, 0, stream>>>(z2_5, ff_w1, ff_b1, f5buf);
    ff2_lnf<<<128, blk, 0, stream>>>(f5buf, ff_w2, ff_b2, t5buf, lnf_g, lnf_b, tfin);
    fin_gemm<<<dim3(23, 8), blk, 0, stream>>>(tfin, fin_w, fin_b, refined5);

    // pass 2 (x2 patched on the fly)
    logits_gemm<1><<<dim3(288, NKS), blk, 0, stream>>>(x, Wchi, Wclo,
        amax, refined5, flag, logitsP);
    softmax_heads<<<4608, blk, 0, stream>>>(logitsP, cconst, out_cls2, out_ext2, nullptr, nullptr,
        nullptr, nullptr);
}